// Round 18
// baseline (222.337 us; speedup 1.0000x reference)
//
#include <hip/hip_runtime.h>
#include <math.h>

// ---------------------------------------------------------------------------
// CellTypeGNN: 2x [SAGE(mean) -> LN -> GELU -> +res] -> SAGE -> GELU -> LN -> Linear
// N=50000, E=800000, D=128, DOUT(conv3)=64, classes=40.
// R17: fix R16's gather-footprint regression. k_aggpost fetched 92MB because
//     z was interleaved in Y[n][256] (512B rows, half-used on gather). Now
//     k_gemmW writes SEPARATE Zb[n][128] / Wb[n][128] (dense 12.8MB z buffer
//     == the proven R15 gather pattern); aggpost gathers Zb, reads Wb/Xres
//     coalesced. Layer 3 uses 64-wide halves. Everything else from R16.
// ---------------------------------------------------------------------------

typedef __attribute__((ext_vector_type(8))) short bf16x8;
typedef __attribute__((ext_vector_type(4))) float f32x4;

#define AS1 __attribute__((address_space(1)))
#define AS3 __attribute__((address_space(3)))

#define NWG 256      // workgroups in hist/scat passes
#define NBK 196      // buckets: dst>>8 (196*256 = 50176 >= n)
#define CAP2 6144    // per-bucket sortC capacity (expect ~4082, sigma 64)

__device__ inline float gelu_f(float x) {
    float u = x * (1.0f + 0.044715f * x * x);
    return x / (1.0f + __expf(-1.5957691216057308f * u));
}

__device__ inline float wave_sum(float v) {
#pragma unroll
    for (int d = 32; d > 0; d >>= 1) v += __shfl_xor(v, d);
    return v;
}

__device__ inline ushort f2b(float f) {  // fp32 -> bf16 RNE
    uint u = __float_as_uint(f);
    u += 0x7fffu + ((u >> 16) & 1u);
    return (ushort)(u >> 16);
}

__device__ inline float b2f(ushort h) { return __uint_as_float((uint)h << 16); }

// ---------------- CSR build: hist -> scan -> scatter -> bucket sort ----------

__global__ __launch_bounds__(256) void k_hist(const int* __restrict__ dst, int e,
                                              int* __restrict__ cnts) {
    __shared__ int h[NBK];
    const int tid = threadIdx.x;
    const int wg = blockIdx.x;
    for (int i = tid; i < NBK; i += 256) h[i] = 0;
    __syncthreads();
    const int ch = (e + NWG - 1) / NWG;
    const int lo = wg * ch;
    const int hi = min(e, lo + ch);
    for (int i = lo + tid; i < hi; i += 256) atomicAdd(&h[dst[i] >> 8], 1);
    __syncthreads();
    for (int i = tid; i < NBK; i += 256) cnts[i * NWG + wg] = h[i];
}

__global__ __launch_bounds__(256) void k_scanP1(const int* __restrict__ in,
                                                int* __restrict__ out,
                                                int* __restrict__ part, int m) {
    __shared__ int sm[256];
    const int tid = threadIdx.x;
    const int base = blockIdx.x * 1024 + tid * 4;
    int4 v = make_int4(0, 0, 0, 0);
    if (base + 3 < m) {
        v = *(const int4*)(in + base);
    } else {
        if (base + 0 < m) v.x = in[base + 0];
        if (base + 1 < m) v.y = in[base + 1];
        if (base + 2 < m) v.z = in[base + 2];
        if (base + 3 < m) v.w = in[base + 3];
    }
    int s = v.x + v.y + v.z + v.w;
    sm[tid] = s;
    __syncthreads();
#pragma unroll
    for (int d = 1; d < 256; d <<= 1) {
        int add = (tid >= d) ? sm[tid - d] : 0;
        __syncthreads();
        sm[tid] += add;
        __syncthreads();
    }
    int ex = (tid ? sm[tid - 1] : 0);
    if (base + 0 < m) out[base + 0] = ex;
    ex += v.x;
    if (base + 1 < m) out[base + 1] = ex;
    ex += v.y;
    if (base + 2 < m) out[base + 2] = ex;
    ex += v.z;
    if (base + 3 < m) out[base + 3] = ex;
    if (tid == 255) part[blockIdx.x] = sm[255];
}

__global__ __launch_bounds__(256) void k_scanP2(int* __restrict__ out,
                                                const int* __restrict__ part, int m) {
    const int tid = threadIdx.x;
    const int bid = blockIdx.x;
    const int lane = tid & 63;
    int s = 0;
    for (int j = lane; j < bid; j += 64) s += part[j];
#pragma unroll
    for (int d = 32; d > 0; d >>= 1) s += __shfl_xor(s, d);
    const int i0 = bid * 1024 + tid * 4;
#pragma unroll
    for (int j = 0; j < 4; ++j) {
        int i = i0 + j;
        if (i < m) out[i] += s;
    }
}

__global__ __launch_bounds__(256) void k_scat(const int* __restrict__ src,
                                              const int* __restrict__ dst, int e,
                                              const int* __restrict__ bases,
                                              uint* __restrict__ pairs) {
    __shared__ int cur[NBK];
    const int tid = threadIdx.x;
    const int wg = blockIdx.x;
    for (int i = tid; i < NBK; i += 256) cur[i] = bases[i * NWG + wg];
    __syncthreads();
    const int ch = (e + NWG - 1) / NWG;
    const int lo = wg * ch;
    const int hi = min(e, lo + ch);
    for (int i = lo + tid; i < hi; i += 256) {
        int d = dst[i];
        int pos = atomicAdd(&cur[d >> 8], 1);
        pairs[pos] = (uint)src[i] | ((uint)(d & 255) << 16);
    }
}

__global__ __launch_bounds__(256) void k_sortC(const uint* __restrict__ pairs,
                                               const int* __restrict__ bases, int e,
                                               int* __restrict__ csr, int* __restrict__ off,
                                               int* __restrict__ cntout, int n) {
    __shared__ int hist[256];
    __shared__ int curl[256];
    __shared__ int sm[256];
    __shared__ int buf[CAP2];
    const int bk = blockIdx.x;
    const int tid = threadIdx.x;
    const int start = bases[bk * NWG];
    const int end = (bk == NBK - 1) ? e : bases[(bk + 1) * NWG];
    int m = end - start;
    if (m > CAP2) m = CAP2;

    hist[tid] = 0;
    __syncthreads();
    for (int i = tid; i < m; i += 256) atomicAdd(&hist[(pairs[start + i] >> 16) & 255], 1);
    __syncthreads();
    int v = hist[tid];
    sm[tid] = v;
    __syncthreads();
#pragma unroll
    for (int d = 1; d < 256; d <<= 1) {
        int add = (tid >= d) ? sm[tid - d] : 0;
        __syncthreads();
        sm[tid] += add;
        __syncthreads();
    }
    int excl = sm[tid] - v;
    int node = (bk << 8) + tid;
    if (node < n) {
        off[node] = start + excl;
        cntout[node] = v;
    }
    curl[tid] = excl;
    __syncthreads();
    for (int i = tid; i < m; i += 256) {
        uint w = pairs[start + i];
        int pos = atomicAdd(&curl[(w >> 16) & 255], 1);
        buf[pos] = (int)(w & 0xffffu);
    }
    __syncthreads();
    for (int i = tid; i < m; i += 256) csr[start + i] = buf[i];
}

// ---------------- casts / weight prep ----------------

__global__ void k_cast(const float* __restrict__ in, ushort* __restrict__ out, int nvec4) {
    int t = blockIdx.x * blockDim.x + threadIdx.x;
    int stride = gridDim.x * blockDim.x;
    for (int i = t; i < nvec4; i += stride) {
        float4 v = ((const float4*)in)[i];
        ushort4 o;
        o.x = f2b(v.x);
        o.y = f2b(v.y);
        o.z = f2b(v.z);
        o.w = f2b(v.w);
        ((ushort4*)out)[i] = o;
    }
}

// Wt[c][k] for c in [0,2*CH), k in [0,K): c<CH ? Wl[k][c] : Wr[k][c-CH]
__global__ void k_wprepW(const float* __restrict__ Wl, const float* __restrict__ Wr,
                         int CH, int K, ushort* __restrict__ Wt) {
    int t = blockIdx.x * blockDim.x + threadIdx.x;
    int total = 2 * CH * K;
    if (t >= total) return;
    int c = t / K, k = t % K;
    float v = (c < CH) ? Wl[(size_t)k * CH + c] : Wr[(size_t)k * CH + (c - CH)];
    Wt[t] = f2b(v);
}

// Wct[c][k] = (c<40) ? Wc[k][c] : 0; [64][64] bf16 (zero-padded cols)
__global__ void k_wprepC(const float* __restrict__ Wc, ushort* __restrict__ Wct) {
    int t = blockIdx.x * blockDim.x + threadIdx.x;
    if (t >= 64 * 64) return;
    int c = t >> 6, k = t & 63;
    float v = (c < 40) ? Wc[k * 40 + c] : 0.f;
    Wct[t] = f2b(v);
}

// ---------------- dense GEMM: [Z|W] = X @ Wt^T (bf16 MFMA, K=128) ------------
// Block = 32 rows x CW cols, 4 waves. A staged via global_load_lds w16
// (linear dest + pre-swizzled source). Z and W stored to SEPARATE dense
// buffers (cols < CH -> Z, else W) so the downstream gather is dense.

template <int CW>
__global__ __launch_bounds__(256) void k_gemmW(const ushort* __restrict__ X,
                                               const ushort* __restrict__ Wt,
                                               ushort* __restrict__ Z,
                                               ushort* __restrict__ Wo, int n) {
    constexpr int CT = CW / 64;   // 4 or 2
    constexpr int CH = CW / 2;    // 128 or 64
    const int tid = threadIdx.x;
    const int wave = tid >> 6;
    const int lane = tid & 63;
    const int l16 = lane & 15;
    const int g4 = lane >> 4;
    const int row0 = blockIdx.x * 32;

    __shared__ __align__(16) ushort As[32 * 128];  // 8 KB: [row][256B]

    // ---- stage A: 2 global_load_lds w16 per wave, pre-swizzled source ----
    {
        const int slot = lane & 15;
#pragma unroll
        for (int i = 0; i < 2; ++i) {
            const int rr = (wave * 2 + i) * 4 + (lane >> 4);  // 0..31
            int gr = row0 + rr;
            if (gr > n - 1) gr = n - 1;
            const int srcb = (slot * 16) ^ ((rr & 7) << 4);
            const char* gp = (const char*)X + (size_t)gr * 256 + srcb;
            char* lp = (char*)As + (wave * 2 + i) * 1024;  // wave-uniform base
            __builtin_amdgcn_global_load_lds((const AS1 void*)gp, (AS3 void*)lp, 16, 0, 0);
        }
    }

    int colv[CT];
#pragma unroll
    for (int ct = 0; ct < CT; ++ct) colv[ct] = (wave * CT + ct) * 16 + l16;

    bf16x8 bfr[CT][4];
#pragma unroll
    for (int ct = 0; ct < CT; ++ct) {
        const ushort* wp = Wt + (size_t)colv[ct] * 128 + g4 * 8;
#pragma unroll
        for (int ks = 0; ks < 4; ++ks) bfr[ct][ks] = *(const bf16x8*)(wp + ks * 32);
    }

    __syncthreads();  // drains vmcnt incl. global_load_lds

    f32x4 acc[2][CT];
#pragma unroll
    for (int rt = 0; rt < 2; ++rt)
#pragma unroll
        for (int ct = 0; ct < CT; ++ct) {
            acc[rt][ct][0] = 0.f;
            acc[rt][ct][1] = 0.f;
            acc[rt][ct][2] = 0.f;
            acc[rt][ct][3] = 0.f;
        }
#pragma unroll
    for (int ks = 0; ks < 4; ++ks) {
        bf16x8 a[2];
#pragma unroll
        for (int rt = 0; rt < 2; ++rt) {
            const int row = rt * 16 + l16;
            a[rt] = *(const bf16x8*)((const char*)As + row * 256 +
                                     ((ks * 64 + g4 * 16) ^ ((row & 7) << 4)));
        }
#pragma unroll
        for (int rt = 0; rt < 2; ++rt)
#pragma unroll
            for (int ct = 0; ct < CT; ++ct)
                acc[rt][ct] = __builtin_amdgcn_mfma_f32_16x16x32_bf16(a[rt], bfr[ct][ks],
                                                                     acc[rt][ct], 0, 0, 0);
    }

#pragma unroll
    for (int rt = 0; rt < 2; ++rt)
#pragma unroll
        for (int reg = 0; reg < 4; ++reg) {
            int r = row0 + rt * 16 + g4 * 4 + reg;
            if (r >= n) continue;
#pragma unroll
            for (int ct = 0; ct < CT; ++ct) {
                int col = colv[ct];
                ushort hv = f2b(acc[rt][ct][reg]);
                if (col < CH)
                    Z[(size_t)r * CH + col] = hv;
                else
                    Wo[(size_t)r * CH + (col - CH)] = hv;
            }
        }
}

// ---------------- aggpost (layers 1,2): gather-mean(Z) + W + bl -> LN -> GELU
// -> +residual -> bf16. Wave per node (8/wave); Z dense [n][128] (2 cols/lane).

__global__ __launch_bounds__(256) void k_aggpost(
    const ushort* __restrict__ Z, const ushort* __restrict__ Wb,
    const ushort* __restrict__ Xres, const int* __restrict__ off,
    const int* __restrict__ cnt, const int* __restrict__ csr,
    const float* __restrict__ bl, const float* __restrict__ g,
    const float* __restrict__ b, ushort* __restrict__ Xout, int n) {
    const int wave = threadIdx.x >> 6;
    const int lane = threadIdx.x & 63;
    const int base = blockIdx.x * 32 + wave * 8;

    const float2 blv = ((const float2*)bl)[lane];
    const float2 gv = ((const float2*)g)[lane];
    const float2 bv = ((const float2*)b)[lane];

#pragma unroll 1
    for (int j = 0; j < 8; ++j) {
        const int i = base + j;
        if (i >= n) return;
        int s0 = off[i];
        int deg = cnt[i];
        int c = 0;
        if (lane < deg) c = csr[s0 + lane];
        float a0 = 0.f, a1 = 0.f;
        const int dcap = deg < 64 ? deg : 64;
        int t = 0;
        for (; t + 3 < dcap; t += 4) {
            int i0 = __shfl(c, t), i1 = __shfl(c, t + 1);
            int i2 = __shfl(c, t + 2), i3 = __shfl(c, t + 3);
            uint u0 = *((const uint*)(Z + (size_t)i0 * 128) + lane);
            uint u1 = *((const uint*)(Z + (size_t)i1 * 128) + lane);
            uint u2 = *((const uint*)(Z + (size_t)i2 * 128) + lane);
            uint u3 = *((const uint*)(Z + (size_t)i3 * 128) + lane);
            a0 += __uint_as_float(u0 << 16) + __uint_as_float(u1 << 16) +
                  __uint_as_float(u2 << 16) + __uint_as_float(u3 << 16);
            a1 += __uint_as_float(u0 & 0xffff0000u) + __uint_as_float(u1 & 0xffff0000u) +
                  __uint_as_float(u2 & 0xffff0000u) + __uint_as_float(u3 & 0xffff0000u);
        }
        for (; t < dcap; ++t) {
            uint u0 = *((const uint*)(Z + (size_t)__shfl(c, t) * 128) + lane);
            a0 += __uint_as_float(u0 << 16);
            a1 += __uint_as_float(u0 & 0xffff0000u);
        }
        for (int tt = s0 + 64; tt < s0 + deg; ++tt) {  // rare deg>64 tail
            uint u0 = *((const uint*)(Z + (size_t)csr[tt] * 128) + lane);
            a0 += __uint_as_float(u0 << 16);
            a1 += __uint_as_float(u0 & 0xffff0000u);
        }
        float inv = 1.0f / (float)(deg > 1 ? deg : 1);
        uint wv = *((const uint*)(Wb + (size_t)i * 128) + lane);
        float h0 = a0 * inv + __uint_as_float(wv << 16) + blv.x;
        float h1 = a1 * inv + __uint_as_float(wv & 0xffff0000u) + blv.y;
        float mu = wave_sum(h0 + h1) * (1.0f / 128.0f);
        float d0 = h0 - mu, d1 = h1 - mu;
        float var = wave_sum(d0 * d0 + d1 * d1) * (1.0f / 128.0f);
        float rs = rsqrtf(var + 1e-5f);
        uint rv = *((const uint*)(Xres + (size_t)i * 128) + lane);
        float y0 = gelu_f(d0 * rs * gv.x + bv.x) + __uint_as_float(rv << 16);
        float y1 = gelu_f(d1 * rs * gv.y + bv.y) + __uint_as_float(rv & 0xffff0000u);
        uint pk = (uint)f2b(y0) | ((uint)f2b(y1) << 16);
        *((uint*)(Xout + (size_t)i * 128) + lane) = pk;
    }
}

// ---------------- aggpost3 (conv_out): gather-mean(Z3)+W3+bl3 -> GELU -> LN --
// Z3 dense [n][64]; 2 nodes per wave-pass using 32 lanes each would complicate;
// keep 1 col/lane (64 lanes cover D=64), footprint 6.4MB (L2-hot).

__global__ __launch_bounds__(256) void k_aggpost3(
    const ushort* __restrict__ Z3, const ushort* __restrict__ W3,
    const int* __restrict__ off, const int* __restrict__ cnt,
    const int* __restrict__ csr, const float* __restrict__ bl3,
    const float* __restrict__ gc, const float* __restrict__ bc,
    ushort* __restrict__ Yout, int n) {
    const int wave = threadIdx.x >> 6;
    const int lane = threadIdx.x & 63;
    const int base = blockIdx.x * 32 + wave * 8;

    const float blv = bl3[lane];
    const float gv = gc[lane];
    const float bv = bc[lane];

#pragma unroll 1
    for (int j = 0; j < 8; ++j) {
        const int i = base + j;
        if (i >= n) return;
        int s0 = off[i];
        int deg = cnt[i];
        int c = 0;
        if (lane < deg) c = csr[s0 + lane];
        float a = 0.f;
        const int dcap = deg < 64 ? deg : 64;
        int t = 0;
        for (; t + 3 < dcap; t += 4) {
            int i0 = __shfl(c, t), i1 = __shfl(c, t + 1);
            int i2 = __shfl(c, t + 2), i3 = __shfl(c, t + 3);
            a += b2f(Z3[(size_t)i0 * 64 + lane]) + b2f(Z3[(size_t)i1 * 64 + lane]) +
                 b2f(Z3[(size_t)i2 * 64 + lane]) + b2f(Z3[(size_t)i3 * 64 + lane]);
        }
        for (; t < dcap; ++t) a += b2f(Z3[(size_t)__shfl(c, t) * 64 + lane]);
        for (int tt = s0 + 64; tt < s0 + deg; ++tt)
            a += b2f(Z3[(size_t)csr[tt] * 64 + lane]);
        float inv = 1.0f / (float)(deg > 1 ? deg : 1);
        float h = a * inv + b2f(W3[(size_t)i * 64 + lane]) + blv;
        float hg = gelu_f(h);  // GELU before classifier LN
        float mu = wave_sum(hg) * (1.0f / 64.0f);
        float d = hg - mu;
        float var = wave_sum(d * d) * (1.0f / 64.0f);
        float y = d * rsqrtf(var + 1e-5f) * gv + bv;
        Yout[(size_t)i * 64 + lane] = f2b(y);
    }
}

// ---------------- classifier matvec: Out = Y @ Wct^T + bcls (pure MFMA) -------

__global__ __launch_bounds__(256) void k_mm(const ushort* __restrict__ Y,
                                            const ushort* __restrict__ Wct,
                                            const float* __restrict__ bcls,
                                            float* __restrict__ Out, int n) {
    const int tid = threadIdx.x;
    const int wave = tid >> 6;
    const int lane = tid & 63;
    const int l16 = lane & 15;
    const int g4 = lane >> 4;
    const int row0 = blockIdx.x * 32;
    const int col = wave * 16 + l16;

    bf16x8 bfr[2];
#pragma unroll
    for (int ks = 0; ks < 2; ++ks)
        bfr[ks] = *(const bf16x8*)(Wct + (size_t)col * 64 + ks * 32 + g4 * 8);

    f32x4 acc[2];
#pragma unroll
    for (int rt = 0; rt < 2; ++rt) {
        acc[rt][0] = 0.f;
        acc[rt][1] = 0.f;
        acc[rt][2] = 0.f;
        acc[rt][3] = 0.f;
    }

    int arow[2];
#pragma unroll
    for (int rt = 0; rt < 2; ++rt) {
        int r = row0 + rt * 16 + l16;
        arow[rt] = (r < n) ? r : (n - 1);
    }

#pragma unroll
    for (int ks = 0; ks < 2; ++ks)
#pragma unroll
        for (int rt = 0; rt < 2; ++rt) {
            bf16x8 a = *(const bf16x8*)(Y + (size_t)arow[rt] * 64 + ks * 32 + g4 * 8);
            acc[rt] = __builtin_amdgcn_mfma_f32_16x16x32_bf16(a, bfr[ks], acc[rt], 0, 0, 0);
        }

    const float bcv = (col < 40) ? bcls[col] : 0.f;
#pragma unroll
    for (int rt = 0; rt < 2; ++rt)
#pragma unroll
        for (int reg = 0; reg < 4; ++reg) {
            int r = row0 + rt * 16 + g4 * 4 + reg;
            if (r < n && col < 40) Out[(size_t)r * 40 + col] = acc[rt][reg] + bcv;
        }
}

// ---------------------------------------------------------------------------

extern "C" void kernel_launch(void* const* d_in, const int* in_sizes, int n_in,
                              void* d_out, int out_size, void* d_ws, size_t ws_size,
                              hipStream_t stream) {
    const float* x   = (const float*)d_in[0];
    const int* ei    = (const int*)d_in[1];
    const float* Wl1 = (const float*)d_in[2];
    const float* bl1 = (const float*)d_in[3];
    const float* Wr1 = (const float*)d_in[4];
    const float* g1  = (const float*)d_in[5];
    const float* b1  = (const float*)d_in[6];
    const float* Wl2 = (const float*)d_in[7];
    const float* bl2 = (const float*)d_in[8];
    const float* Wr2 = (const float*)d_in[9];
    const float* g2  = (const float*)d_in[10];
    const float* b2  = (const float*)d_in[11];
    const float* Wl3 = (const float*)d_in[12];
    const float* bl3 = (const float*)d_in[13];
    const float* Wr3 = (const float*)d_in[14];
    const float* gc  = (const float*)d_in[15];
    const float* bc  = (const float*)d_in[16];
    const float* Wc  = (const float*)d_in[17];
    const float* bcls= (const float*)d_in[18];

    const int n = in_sizes[0] / 128;  // 50000
    const int e = in_sizes[1] / 2;    // 800000
    const int* src = ei;
    const int* dst = ei + e;

    char* w = (char*)d_ws;
    size_t o = 0;
    auto alloc = [&](size_t bytes) -> char* {
        char* p = w + o;
        o = (o + bytes + 511) & ~(size_t)511;
        return p;
    };
    int* cnts    = (int*)alloc((size_t)NBK * NWG * 4);
    int* bases   = (int*)alloc((size_t)NBK * NWG * 4);
    int* part    = (int*)alloc(256 * 4);
    uint* pairs  = (uint*)alloc((size_t)e * 4);
    int* csr     = (int*)alloc((size_t)e * 4);
    int* off     = (int*)alloc((size_t)n * 4);
    int* cnt     = (int*)alloc((size_t)n * 4);
    ushort* xB   = (ushort*)alloc((size_t)n * 128 * 2);
    ushort* Zb   = (ushort*)alloc((size_t)n * 128 * 2);  // dense z (12.8 MB)
    ushort* Wb   = (ushort*)alloc((size_t)n * 128 * 2);  // dense w
    ushort* xaB  = (ushort*)alloc((size_t)n * 128 * 2);
    ushort* xbB  = (ushort*)alloc((size_t)n * 128 * 2);
    ushort* yB   = (ushort*)alloc((size_t)n * 64 * 2);
    ushort* W1c  = (ushort*)alloc((size_t)256 * 128 * 2);
    ushort* W2c  = (ushort*)alloc((size_t)256 * 128 * 2);
    ushort* W3c  = (ushort*)alloc((size_t)128 * 128 * 2);
    ushort* Wct  = (ushort*)alloc((size_t)64 * 64 * 2);
    (void)ws_size;

    // CSR build: hist -> scan -> scatter -> per-bucket sort (no global atomics)
    const int m = NBK * NWG;              // 50176
    const int sblk = (m + 1023) / 1024;   // 49
    k_hist<<<NWG, 256, 0, stream>>>(dst, e, cnts);
    k_scanP1<<<sblk, 256, 0, stream>>>(cnts, bases, part, m);
    k_scanP2<<<sblk, 256, 0, stream>>>(bases, part, m);
    k_scat<<<NWG, 256, 0, stream>>>(src, dst, e, bases, pairs);
    k_sortC<<<NBK, 256, 0, stream>>>(pairs, bases, e, csr, off, cnt, n);

    k_cast<<<2048, 256, 0, stream>>>(x, xB, n * 128 / 4);
    k_wprepW<<<(256 * 128 + 255) / 256, 256, 0, stream>>>(Wl1, Wr1, 128, 128, W1c);
    k_wprepW<<<(256 * 128 + 255) / 256, 256, 0, stream>>>(Wl2, Wr2, 128, 128, W2c);
    k_wprepW<<<(128 * 128 + 255) / 256, 256, 0, stream>>>(Wl3, Wr3, 64, 128, W3c);
    k_wprepC<<<16, 256, 0, stream>>>(Wc, Wct);

    const int gg = (n + 31) / 32;

    // layer 1: [Z|W] = xB @ [Wl1|Wr1]; agg(Z)+W+bl1 -> LN -> GELU -> +xB
    k_gemmW<256><<<gg, 256, 0, stream>>>(xB, W1c, Zb, Wb, n);
    k_aggpost<<<gg, 256, 0, stream>>>(Zb, Wb, xB, off, cnt, csr, bl1, g1, b1, xaB, n);
    // layer 2
    k_gemmW<256><<<gg, 256, 0, stream>>>(xaB, W2c, Zb, Wb, n);
    k_aggpost<<<gg, 256, 0, stream>>>(Zb, Wb, xaB, off, cnt, csr, bl2, g2, b2, xbB, n);
    // conv_out: [Z3|W3] = xbB @ [Wl3|Wr3]; agg(Z3)+W3+bl3 -> GELU -> LN(gc,bc)
    k_gemmW<128><<<gg, 256, 0, stream>>>(xbB, W3c, Zb, Wb, n);
    k_aggpost3<<<gg, 256, 0, stream>>>(Zb, Wb, off, cnt, csr, bl3, gc, bc, yB, n);
    // classifier matvec
    k_mm<<<gg, 256, 0, stream>>>(yB, Wct, bcls, (float*)d_out, n);
}

// Round 19
// 207.388 us; speedup vs baseline: 1.0721x; 1.0721x over previous
//
#include <hip/hip_runtime.h>
#include <math.h>

// ---------------------------------------------------------------------------
// CellTypeGNN: 2x [SAGE(mean) -> LN -> GELU -> +res] -> SAGE -> GELU -> LN -> Linear
// N=50000, E=800000, D=128, DOUT(conv3)=64, classes=40.
// R18 hybrid: layers 1-2 = R15 form (agg -> fused gemm, 256-wide K, verified
//     202us path): gather runs on 128-dim x (205MB logical, rooflined).
//     Layer 3 = R17 form (gemm first -> gather the 64-dim projection):
//     halves the layer-3 gather volume (205 -> 102MB logical, ~140MB total
//     vs ~250). R17 A/B showed de-interleaving is neutral and the gather is
//     at ~92% of achievable BW -> only byte-count reduction helps.
// ---------------------------------------------------------------------------

typedef __attribute__((ext_vector_type(8))) short bf16x8;
typedef __attribute__((ext_vector_type(4))) float f32x4;

#define AS1 __attribute__((address_space(1)))
#define AS3 __attribute__((address_space(3)))

#define NWG 256      // workgroups in hist/scat passes
#define NBK 196      // buckets: dst>>8 (196*256 = 50176 >= n)
#define CAP2 6144    // per-bucket sortC capacity (expect ~4082, sigma 64)

__device__ inline float gelu_f(float x) {
    float u = x * (1.0f + 0.044715f * x * x);
    return x / (1.0f + __expf(-1.5957691216057308f * u));
}

__device__ inline float wave_sum(float v) {
#pragma unroll
    for (int d = 32; d > 0; d >>= 1) v += __shfl_xor(v, d);
    return v;
}

__device__ inline ushort f2b(float f) {  // fp32 -> bf16 RNE
    uint u = __float_as_uint(f);
    u += 0x7fffu + ((u >> 16) & 1u);
    return (ushort)(u >> 16);
}

__device__ inline float b2f(ushort h) { return __uint_as_float((uint)h << 16); }

// ---------------- CSR build: hist -> scan -> scatter -> bucket sort ----------

__global__ __launch_bounds__(256) void k_hist(const int* __restrict__ dst, int e,
                                              int* __restrict__ cnts) {
    __shared__ int h[NBK];
    const int tid = threadIdx.x;
    const int wg = blockIdx.x;
    for (int i = tid; i < NBK; i += 256) h[i] = 0;
    __syncthreads();
    const int ch = (e + NWG - 1) / NWG;
    const int lo = wg * ch;
    const int hi = min(e, lo + ch);
    for (int i = lo + tid; i < hi; i += 256) atomicAdd(&h[dst[i] >> 8], 1);
    __syncthreads();
    for (int i = tid; i < NBK; i += 256) cnts[i * NWG + wg] = h[i];
}

__global__ __launch_bounds__(256) void k_scanP1(const int* __restrict__ in,
                                                int* __restrict__ out,
                                                int* __restrict__ part, int m) {
    __shared__ int sm[256];
    const int tid = threadIdx.x;
    const int base = blockIdx.x * 1024 + tid * 4;
    int4 v = make_int4(0, 0, 0, 0);
    if (base + 3 < m) {
        v = *(const int4*)(in + base);
    } else {
        if (base + 0 < m) v.x = in[base + 0];
        if (base + 1 < m) v.y = in[base + 1];
        if (base + 2 < m) v.z = in[base + 2];
        if (base + 3 < m) v.w = in[base + 3];
    }
    int s = v.x + v.y + v.z + v.w;
    sm[tid] = s;
    __syncthreads();
#pragma unroll
    for (int d = 1; d < 256; d <<= 1) {
        int add = (tid >= d) ? sm[tid - d] : 0;
        __syncthreads();
        sm[tid] += add;
        __syncthreads();
    }
    int ex = (tid ? sm[tid - 1] : 0);
    if (base + 0 < m) out[base + 0] = ex;
    ex += v.x;
    if (base + 1 < m) out[base + 1] = ex;
    ex += v.y;
    if (base + 2 < m) out[base + 2] = ex;
    ex += v.z;
    if (base + 3 < m) out[base + 3] = ex;
    if (tid == 255) part[blockIdx.x] = sm[255];
}

__global__ __launch_bounds__(256) void k_scanP2(int* __restrict__ out,
                                                const int* __restrict__ part, int m) {
    const int tid = threadIdx.x;
    const int bid = blockIdx.x;
    const int lane = tid & 63;
    int s = 0;
    for (int j = lane; j < bid; j += 64) s += part[j];
#pragma unroll
    for (int d = 32; d > 0; d >>= 1) s += __shfl_xor(s, d);
    const int i0 = bid * 1024 + tid * 4;
#pragma unroll
    for (int j = 0; j < 4; ++j) {
        int i = i0 + j;
        if (i < m) out[i] += s;
    }
}

__global__ __launch_bounds__(256) void k_scat(const int* __restrict__ src,
                                              const int* __restrict__ dst, int e,
                                              const int* __restrict__ bases,
                                              uint* __restrict__ pairs) {
    __shared__ int cur[NBK];
    const int tid = threadIdx.x;
    const int wg = blockIdx.x;
    for (int i = tid; i < NBK; i += 256) cur[i] = bases[i * NWG + wg];
    __syncthreads();
    const int ch = (e + NWG - 1) / NWG;
    const int lo = wg * ch;
    const int hi = min(e, lo + ch);
    for (int i = lo + tid; i < hi; i += 256) {
        int d = dst[i];
        int pos = atomicAdd(&cur[d >> 8], 1);
        pairs[pos] = (uint)src[i] | ((uint)(d & 255) << 16);
    }
}

__global__ __launch_bounds__(256) void k_sortC(const uint* __restrict__ pairs,
                                               const int* __restrict__ bases, int e,
                                               int* __restrict__ csr, int* __restrict__ off,
                                               int* __restrict__ cntout, int n) {
    __shared__ int hist[256];
    __shared__ int curl[256];
    __shared__ int sm[256];
    __shared__ int buf[CAP2];
    const int bk = blockIdx.x;
    const int tid = threadIdx.x;
    const int start = bases[bk * NWG];
    const int end = (bk == NBK - 1) ? e : bases[(bk + 1) * NWG];
    int m = end - start;
    if (m > CAP2) m = CAP2;

    hist[tid] = 0;
    __syncthreads();
    for (int i = tid; i < m; i += 256) atomicAdd(&hist[(pairs[start + i] >> 16) & 255], 1);
    __syncthreads();
    int v = hist[tid];
    sm[tid] = v;
    __syncthreads();
#pragma unroll
    for (int d = 1; d < 256; d <<= 1) {
        int add = (tid >= d) ? sm[tid - d] : 0;
        __syncthreads();
        sm[tid] += add;
        __syncthreads();
    }
    int excl = sm[tid] - v;
    int node = (bk << 8) + tid;
    if (node < n) {
        off[node] = start + excl;
        cntout[node] = v;
    }
    curl[tid] = excl;
    __syncthreads();
    for (int i = tid; i < m; i += 256) {
        uint w = pairs[start + i];
        int pos = atomicAdd(&curl[(w >> 16) & 255], 1);
        buf[pos] = (int)(w & 0xffffu);
    }
    __syncthreads();
    for (int i = tid; i < m; i += 256) csr[start + i] = buf[i];
}

// ---------------- casts / weight prep ----------------

__global__ void k_cast(const float* __restrict__ in, ushort* __restrict__ out, int nvec4) {
    int t = blockIdx.x * blockDim.x + threadIdx.x;
    int stride = gridDim.x * blockDim.x;
    for (int i = t; i < nvec4; i += stride) {
        float4 v = ((const float4*)in)[i];
        ushort4 o;
        o.x = f2b(v.x);
        o.y = f2b(v.y);
        o.z = f2b(v.z);
        o.w = f2b(v.w);
        ((ushort4*)out)[i] = o;
    }
}

// Wt[c][k] = (k<KH ? Wl[k][c] : Wr[k-KH][c]); Wt is [C][2*KH] bf16. (layers 1-2)
__global__ void k_wprep(const float* __restrict__ Wl, const float* __restrict__ Wr,
                        int KH, int C, ushort* __restrict__ Wt) {
    int t = blockIdx.x * blockDim.x + threadIdx.x;
    int total = C * 2 * KH;
    if (t >= total) return;
    int c = t / (2 * KH), k = t % (2 * KH);
    float v = (k < KH) ? Wl[(size_t)k * C + c] : Wr[(size_t)(k - KH) * C + c];
    Wt[t] = f2b(v);
}

// layer-3 combined: Wt[c][k], c in [0,128): c<64 ? Wl3[k][c] : Wr3[k][c-64]
__global__ void k_wprepW3(const float* __restrict__ Wl, const float* __restrict__ Wr,
                          ushort* __restrict__ Wt) {
    int t = blockIdx.x * blockDim.x + threadIdx.x;
    if (t >= 128 * 128) return;
    int c = t >> 7, k = t & 127;
    float v = (c < 64) ? Wl[(size_t)k * 64 + c] : Wr[(size_t)k * 64 + (c - 64)];
    Wt[t] = f2b(v);
}

// Wct[c][k] = (c<40) ? Wc[k][c] : 0; [64][64] bf16 (zero-padded cols)
__global__ void k_wprepC(const float* __restrict__ Wc, ushort* __restrict__ Wct) {
    int t = blockIdx.x * blockDim.x + threadIdx.x;
    if (t >= 64 * 64) return;
    int c = t >> 6, k = t & 63;
    float v = (c < 40) ? Wc[k * 40 + c] : 0.f;
    Wct[t] = f2b(v);
}

// ---------------- mean aggregation (layers 1-2; bf16, fp32 accum) ------------

__global__ __launch_bounds__(256) void k_agg(const ushort* __restrict__ X,
                                             const int* __restrict__ off,
                                             const int* __restrict__ cnt,
                                             const int* __restrict__ csr,
                                             ushort* __restrict__ agg, int n) {
    const int wave = threadIdx.x >> 6;
    const int lane = threadIdx.x & 63;
    const int base = blockIdx.x * 32 + wave * 8;
#pragma unroll 1
    for (int j = 0; j < 8; ++j) {
        const int i = base + j;
        if (i >= n) return;
        int s0 = off[i];
        int deg = cnt[i];
        int c = 0;
        if (lane < deg) c = csr[s0 + lane];
        float a0 = 0.f, a1 = 0.f;
        const int dcap = deg < 64 ? deg : 64;
        int t = 0;
        for (; t + 3 < dcap; t += 4) {
            int i0 = __shfl(c, t), i1 = __shfl(c, t + 1);
            int i2 = __shfl(c, t + 2), i3 = __shfl(c, t + 3);
            uint u0 = *((const uint*)(X + (size_t)i0 * 128) + lane);
            uint u1 = *((const uint*)(X + (size_t)i1 * 128) + lane);
            uint u2 = *((const uint*)(X + (size_t)i2 * 128) + lane);
            uint u3 = *((const uint*)(X + (size_t)i3 * 128) + lane);
            a0 += __uint_as_float(u0 << 16) + __uint_as_float(u1 << 16) +
                  __uint_as_float(u2 << 16) + __uint_as_float(u3 << 16);
            a1 += __uint_as_float(u0 & 0xffff0000u) + __uint_as_float(u1 & 0xffff0000u) +
                  __uint_as_float(u2 & 0xffff0000u) + __uint_as_float(u3 & 0xffff0000u);
        }
        for (; t < dcap; ++t) {
            uint u0 = *((const uint*)(X + (size_t)__shfl(c, t) * 128) + lane);
            a0 += __uint_as_float(u0 << 16);
            a1 += __uint_as_float(u0 & 0xffff0000u);
        }
        for (int tt = s0 + 64; tt < s0 + deg; ++tt) {  // rare deg>64 tail
            uint u0 = *((const uint*)(X + (size_t)csr[tt] * 128) + lane);
            a0 += __uint_as_float(u0 << 16);
            a1 += __uint_as_float(u0 & 0xffff0000u);
        }
        float inv = 1.0f / (float)(deg > 1 ? deg : 1);
        uint pk = (uint)f2b(a0 * inv) | ((uint)f2b(a1 * inv) << 16);
        *((uint*)(agg + (size_t)i * 128) + lane) = pk;
    }
}

// ---------------- MFMA SAGE GEMM (layers 1-2; R15 verified) ------------------
// Block = 32 rows x 128 cols, 4 waves, K=256 ([Agg|Xb]). A staged via
// global_load_lds w16, linear LDS dest + pre-swizzled source (XOR (row&7)<<4).
// Epilogue: LN+GELU+residual(Xb from LDS) -> bf16 [n][128].

__global__ __launch_bounds__(256) void k_gemm(
    const ushort* __restrict__ Agg, const ushort* __restrict__ Xb,
    const ushort* __restrict__ Wt, const float* __restrict__ bias,
    const float* __restrict__ g, const float* __restrict__ b,
    ushort* __restrict__ OutB, int n) {
    constexpr int CT = 2;
    const int tid = threadIdx.x;
    const int wave = tid >> 6;
    const int lane = tid & 63;
    const int l16 = lane & 15;
    const int g4 = lane >> 4;
    const int row0 = blockIdx.x * 32;

    __shared__ __align__(16) ushort As[32 * 256];  // 16 KB linear [row][512B]
    __shared__ float sP[32][4];
    __shared__ float qP[32][4];

    // ---- stage A: direct global->LDS DMA, pre-swizzled per-lane source ----
    {
        const int slot = lane & 31;
#pragma unroll
        for (int i = 0; i < 4; ++i) {
            const int rr = (wave * 4 + i) * 2 + (lane >> 5);  // 0..31
            int gr = row0 + rr;
            if (gr > n - 1) gr = n - 1;
            const int srcb = (slot * 16) ^ ((rr & 7) << 4);
            const char* gp = (srcb < 256)
                                 ? (const char*)Agg + (size_t)gr * 256 + srcb
                                 : (const char*)Xb + (size_t)gr * 256 + (srcb - 256);
            char* lp = (char*)As + (wave * 4 + i) * 1024;  // wave-uniform base
            __builtin_amdgcn_global_load_lds((const AS1 void*)gp, (AS3 void*)lp, 16, 0, 0);
        }
    }

    int colv[CT];
#pragma unroll
    for (int ct = 0; ct < CT; ++ct) colv[ct] = (wave * CT + ct) * 16 + l16;

    bf16x8 bfr[CT][8];
#pragma unroll
    for (int ct = 0; ct < CT; ++ct) {
        const ushort* wp = Wt + (size_t)colv[ct] * 256 + g4 * 8;
#pragma unroll
        for (int ks = 0; ks < 8; ++ks) bfr[ct][ks] = *(const bf16x8*)(wp + ks * 32);
    }
    float biasv[CT], gv[CT], bbv[CT];
#pragma unroll
    for (int ct = 0; ct < CT; ++ct) {
        biasv[ct] = bias[colv[ct]];
        gv[ct] = g[colv[ct]];
        bbv[ct] = b[colv[ct]];
    }

    __syncthreads();  // drains vmcnt incl. global_load_lds

    f32x4 acc[2][CT];
#pragma unroll
    for (int rt = 0; rt < 2; ++rt)
#pragma unroll
        for (int ct = 0; ct < CT; ++ct) {
            acc[rt][ct][0] = 0.f;
            acc[rt][ct][1] = 0.f;
            acc[rt][ct][2] = 0.f;
            acc[rt][ct][3] = 0.f;
        }
#pragma unroll
    for (int ks = 0; ks < 8; ++ks) {
        bf16x8 a[2];
#pragma unroll
        for (int rt = 0; rt < 2; ++rt) {
            const int row = rt * 16 + l16;
            a[rt] = *(const bf16x8*)((const char*)As + row * 512 +
                                     ((ks * 64 + g4 * 16) ^ ((row & 7) << 4)));
        }
#pragma unroll
        for (int rt = 0; rt < 2; ++rt)
#pragma unroll
            for (int ct = 0; ct < CT; ++ct)
                acc[rt][ct] = __builtin_amdgcn_mfma_f32_16x16x32_bf16(a[rt], bfr[ct][ks],
                                                                     acc[rt][ct], 0, 0, 0);
    }

    float v[2][4][CT];
    float sv[2][4], qv[2][4];
#pragma unroll
    for (int rt = 0; rt < 2; ++rt)
#pragma unroll
        for (int reg = 0; reg < 4; ++reg) {
            float s = 0.f, q = 0.f;
#pragma unroll
            for (int ct = 0; ct < CT; ++ct) {
                float tv = acc[rt][ct][reg] + biasv[ct];
                v[rt][reg][ct] = tv;
                s += tv;
                q += tv * tv;
            }
            sv[rt][reg] = s;
            qv[rt][reg] = q;
        }
#pragma unroll
    for (int m = 1; m < 16; m <<= 1)
#pragma unroll
        for (int rt = 0; rt < 2; ++rt)
#pragma unroll
            for (int reg = 0; reg < 4; ++reg) {
                sv[rt][reg] += __shfl_xor(sv[rt][reg], m);
                qv[rt][reg] += __shfl_xor(qv[rt][reg], m);
            }
    if (l16 == 0) {
#pragma unroll
        for (int rt = 0; rt < 2; ++rt)
#pragma unroll
            for (int reg = 0; reg < 4; ++reg) {
                int rib = rt * 16 + g4 * 4 + reg;
                sP[rib][wave] = sv[rt][reg];
                qP[rib][wave] = qv[rt][reg];
            }
    }
    __syncthreads();
#pragma unroll
    for (int rt = 0; rt < 2; ++rt) {
#pragma unroll
        for (int reg = 0; reg < 4; ++reg) {
            int rib = rt * 16 + g4 * 4 + reg;
            float s = sP[rib][0] + sP[rib][1] + sP[rib][2] + sP[rib][3];
            float q = qP[rib][0] + qP[rib][1] + qP[rib][2] + qP[rib][3];
            float mu = s * (1.0f / 128.0f);
            float var = q * (1.0f / 128.0f) - mu * mu;
            float rs = rsqrtf(fmaxf(var, 0.f) + 1e-5f);
            int r = row0 + rib;
            if (r >= n) continue;
#pragma unroll
            for (int ct = 0; ct < CT; ++ct) {
                float y = (v[rt][reg][ct] - mu) * rs * gv[ct] + bbv[ct];
                ushort rh = *(const ushort*)((const char*)As + rib * 512 +
                                             ((256 + 2 * colv[ct]) ^ ((rib & 7) << 4)));
                y = gelu_f(y) + b2f(rh);
                OutB[(size_t)r * 128 + colv[ct]] = f2b(y);
            }
        }
    }
}

// ---------------- layer-3 dense GEMM: [Z3|W3] = X @ W3c^T (K=128) ------------
// Block = 32 rows x 128 cols, 4 waves. A (256B rows) via global_load_lds w16.

__global__ __launch_bounds__(256) void k_gemmW3(const ushort* __restrict__ X,
                                                const ushort* __restrict__ Wt,
                                                ushort* __restrict__ Z,
                                                ushort* __restrict__ Wo, int n) {
    constexpr int CT = 2;
    const int tid = threadIdx.x;
    const int wave = tid >> 6;
    const int lane = tid & 63;
    const int l16 = lane & 15;
    const int g4 = lane >> 4;
    const int row0 = blockIdx.x * 32;

    __shared__ __align__(16) ushort As[32 * 128];  // 8 KB: [row][256B]

    {
        const int slot = lane & 15;
#pragma unroll
        for (int i = 0; i < 2; ++i) {
            const int rr = (wave * 2 + i) * 4 + (lane >> 4);  // 0..31
            int gr = row0 + rr;
            if (gr > n - 1) gr = n - 1;
            const int srcb = (slot * 16) ^ ((rr & 7) << 4);
            const char* gp = (const char*)X + (size_t)gr * 256 + srcb;
            char* lp = (char*)As + (wave * 2 + i) * 1024;
            __builtin_amdgcn_global_load_lds((const AS1 void*)gp, (AS3 void*)lp, 16, 0, 0);
        }
    }

    int colv[CT];
#pragma unroll
    for (int ct = 0; ct < CT; ++ct) colv[ct] = (wave * CT + ct) * 16 + l16;

    bf16x8 bfr[CT][4];
#pragma unroll
    for (int ct = 0; ct < CT; ++ct) {
        const ushort* wp = Wt + (size_t)colv[ct] * 128 + g4 * 8;
#pragma unroll
        for (int ks = 0; ks < 4; ++ks) bfr[ct][ks] = *(const bf16x8*)(wp + ks * 32);
    }

    __syncthreads();

    f32x4 acc[2][CT];
#pragma unroll
    for (int rt = 0; rt < 2; ++rt)
#pragma unroll
        for (int ct = 0; ct < CT; ++ct) {
            acc[rt][ct][0] = 0.f;
            acc[rt][ct][1] = 0.f;
            acc[rt][ct][2] = 0.f;
            acc[rt][ct][3] = 0.f;
        }
#pragma unroll
    for (int ks = 0; ks < 4; ++ks) {
        bf16x8 a[2];
#pragma unroll
        for (int rt = 0; rt < 2; ++rt) {
            const int row = rt * 16 + l16;
            a[rt] = *(const bf16x8*)((const char*)As + row * 256 +
                                     ((ks * 64 + g4 * 16) ^ ((row & 7) << 4)));
        }
#pragma unroll
        for (int rt = 0; rt < 2; ++rt)
#pragma unroll
            for (int ct = 0; ct < CT; ++ct)
                acc[rt][ct] = __builtin_amdgcn_mfma_f32_16x16x32_bf16(a[rt], bfr[ct][ks],
                                                                     acc[rt][ct], 0, 0, 0);
    }

#pragma unroll
    for (int rt = 0; rt < 2; ++rt)
#pragma unroll
        for (int reg = 0; reg < 4; ++reg) {
            int r = row0 + rt * 16 + g4 * 4 + reg;
            if (r >= n) continue;
#pragma unroll
            for (int ct = 0; ct < CT; ++ct) {
                int col = colv[ct];
                ushort hv = f2b(acc[rt][ct][reg]);
                if (col < 64)
                    Z[(size_t)r * 64 + col] = hv;
                else
                    Wo[(size_t)r * 64 + (col - 64)] = hv;
            }
        }
}

// ---------------- aggpost3 (conv_out): gather-mean(Z3)+W3+bl3 -> GELU -> LN --

__global__ __launch_bounds__(256) void k_aggpost3(
    const ushort* __restrict__ Z3, const ushort* __restrict__ W3,
    const int* __restrict__ off, const int* __restrict__ cnt,
    const int* __restrict__ csr, const float* __restrict__ bl3,
    const float* __restrict__ gc, const float* __restrict__ bc,
    ushort* __restrict__ Yout, int n) {
    const int wave = threadIdx.x >> 6;
    const int lane = threadIdx.x & 63;
    const int base = blockIdx.x * 32 + wave * 8;

    const float blv = bl3[lane];
    const float gv = gc[lane];
    const float bv = bc[lane];

#pragma unroll 1
    for (int j = 0; j < 8; ++j) {
        const int i = base + j;
        if (i >= n) return;
        int s0 = off[i];
        int deg = cnt[i];
        int c = 0;
        if (lane < deg) c = csr[s0 + lane];
        float a = 0.f;
        const int dcap = deg < 64 ? deg : 64;
        int t = 0;
        for (; t + 3 < dcap; t += 4) {
            int i0 = __shfl(c, t), i1 = __shfl(c, t + 1);
            int i2 = __shfl(c, t + 2), i3 = __shfl(c, t + 3);
            a += b2f(Z3[(size_t)i0 * 64 + lane]) + b2f(Z3[(size_t)i1 * 64 + lane]) +
                 b2f(Z3[(size_t)i2 * 64 + lane]) + b2f(Z3[(size_t)i3 * 64 + lane]);
        }
        for (; t < dcap; ++t) a += b2f(Z3[(size_t)__shfl(c, t) * 64 + lane]);
        for (int tt = s0 + 64; tt < s0 + deg; ++tt)
            a += b2f(Z3[(size_t)csr[tt] * 64 + lane]);
        float inv = 1.0f / (float)(deg > 1 ? deg : 1);
        float h = a * inv + b2f(W3[(size_t)i * 64 + lane]) + blv;
        float hg = gelu_f(h);  // GELU before classifier LN
        float mu = wave_sum(hg) * (1.0f / 64.0f);
        float d = hg - mu;
        float var = wave_sum(d * d) * (1.0f / 64.0f);
        float y = d * rsqrtf(var + 1e-5f) * gv + bv;
        Yout[(size_t)i * 64 + lane] = f2b(y);
    }
}

// ---------------- classifier matvec: Out = Y @ Wct^T + bcls (pure MFMA) -------

__global__ __launch_bounds__(256) void k_mm(const ushort* __restrict__ Y,
                                            const ushort* __restrict__ Wct,
                                            const float* __restrict__ bcls,
                                            float* __restrict__ Out, int n) {
    const int tid = threadIdx.x;
    const int wave = tid >> 6;
    const int lane = tid & 63;
    const int l16 = lane & 15;
    const int g4 = lane >> 4;
    const int row0 = blockIdx.x * 32;
    const int col = wave * 16 + l16;

    bf16x8 bfr[2];
#pragma unroll
    for (int ks = 0; ks < 2; ++ks)
        bfr[ks] = *(const bf16x8*)(Wct + (size_t)col * 64 + ks * 32 + g4 * 8);

    f32x4 acc[2];
#pragma unroll
    for (int rt = 0; rt < 2; ++rt) {
        acc[rt][0] = 0.f;
        acc[rt][1] = 0.f;
        acc[rt][2] = 0.f;
        acc[rt][3] = 0.f;
    }

    int arow[2];
#pragma unroll
    for (int rt = 0; rt < 2; ++rt) {
        int r = row0 + rt * 16 + l16;
        arow[rt] = (r < n) ? r : (n - 1);
    }

#pragma unroll
    for (int ks = 0; ks < 2; ++ks)
#pragma unroll
        for (int rt = 0; rt < 2; ++rt) {
            bf16x8 a = *(const bf16x8*)(Y + (size_t)arow[rt] * 64 + ks * 32 + g4 * 8);
            acc[rt] = __builtin_amdgcn_mfma_f32_16x16x32_bf16(a, bfr[ks], acc[rt], 0, 0, 0);
        }

    const float bcv = (col < 40) ? bcls[col] : 0.f;
#pragma unroll
    for (int rt = 0; rt < 2; ++rt)
#pragma unroll
        for (int reg = 0; reg < 4; ++reg) {
            int r = row0 + rt * 16 + g4 * 4 + reg;
            if (r < n && col < 40) Out[(size_t)r * 40 + col] = acc[rt][reg] + bcv;
        }
}

// ---------------------------------------------------------------------------

extern "C" void kernel_launch(void* const* d_in, const int* in_sizes, int n_in,
                              void* d_out, int out_size, void* d_ws, size_t ws_size,
                              hipStream_t stream) {
    const float* x   = (const float*)d_in[0];
    const int* ei    = (const int*)d_in[1];
    const float* Wl1 = (const float*)d_in[2];
    const float* bl1 = (const float*)d_in[3];
    const float* Wr1 = (const float*)d_in[4];
    const float* g1  = (const float*)d_in[5];
    const float* b1  = (const float*)d_in[6];
    const float* Wl2 = (const float*)d_in[7];
    const float* bl2 = (const float*)d_in[8];
    const float* Wr2 = (const float*)d_in[9];
    const float* g2  = (const float*)d_in[10];
    const float* b2  = (const float*)d_in[11];
    const float* Wl3 = (const float*)d_in[12];
    const float* bl3 = (const float*)d_in[13];
    const float* Wr3 = (const float*)d_in[14];
    const float* gc  = (const float*)d_in[15];
    const float* bc  = (const float*)d_in[16];
    const float* Wc  = (const float*)d_in[17];
    const float* bcls= (const float*)d_in[18];

    const int n = in_sizes[0] / 128;  // 50000
    const int e = in_sizes[1] / 2;    // 800000
    const int* src = ei;
    const int* dst = ei + e;

    char* w = (char*)d_ws;
    size_t o = 0;
    auto alloc = [&](size_t bytes) -> char* {
        char* p = w + o;
        o = (o + bytes + 511) & ~(size_t)511;
        return p;
    };
    int* cnts    = (int*)alloc((size_t)NBK * NWG * 4);
    int* bases   = (int*)alloc((size_t)NBK * NWG * 4);
    int* part    = (int*)alloc(256 * 4);
    uint* pairs  = (uint*)alloc((size_t)e * 4);
    int* csr     = (int*)alloc((size_t)e * 4);
    int* off     = (int*)alloc((size_t)n * 4);
    int* cnt     = (int*)alloc((size_t)n * 4);
    ushort* xB   = (ushort*)alloc((size_t)n * 128 * 2);
    ushort* aggB = (ushort*)alloc((size_t)n * 128 * 2);
    ushort* xaB  = (ushort*)alloc((size_t)n * 128 * 2);
    ushort* xbB  = (ushort*)alloc((size_t)n * 128 * 2);
    ushort* Zb   = (ushort*)alloc((size_t)n * 64 * 2);
    ushort* Wb   = (ushort*)alloc((size_t)n * 64 * 2);
    ushort* yB   = (ushort*)alloc((size_t)n * 64 * 2);
    ushort* W1t  = (ushort*)alloc((size_t)128 * 256 * 2);
    ushort* W2t  = (ushort*)alloc((size_t)128 * 256 * 2);
    ushort* W3c  = (ushort*)alloc((size_t)128 * 128 * 2);
    ushort* Wct  = (ushort*)alloc((size_t)64 * 64 * 2);
    (void)ws_size;

    // CSR build: hist -> scan -> scatter -> per-bucket sort (no global atomics)
    const int m = NBK * NWG;              // 50176
    const int sblk = (m + 1023) / 1024;   // 49
    k_hist<<<NWG, 256, 0, stream>>>(dst, e, cnts);
    k_scanP1<<<sblk, 256, 0, stream>>>(cnts, bases, part, m);
    k_scanP2<<<sblk, 256, 0, stream>>>(bases, part, m);
    k_scat<<<NWG, 256, 0, stream>>>(src, dst, e, bases, pairs);
    k_sortC<<<NBK, 256, 0, stream>>>(pairs, bases, e, csr, off, cnt, n);

    k_cast<<<2048, 256, 0, stream>>>(x, xB, n * 128 / 4);
    k_wprep<<<(128 * 256 + 255) / 256, 256, 0, stream>>>(Wl1, Wr1, 128, 128, W1t);
    k_wprep<<<(128 * 256 + 255) / 256, 256, 0, stream>>>(Wl2, Wr2, 128, 128, W2t);
    k_wprepW3<<<(128 * 128 + 255) / 256, 256, 0, stream>>>(Wl3, Wr3, W3c);
    k_wprepC<<<16, 256, 0, stream>>>(Wc, Wct);

    const int gg = (n + 31) / 32;

    // layer 1 (R15 form): agg -> fused gemm(LN+GELU+res)
    k_agg<<<gg, 256, 0, stream>>>(xB, off, cnt, csr, aggB, n);
    k_gemm<<<gg, 256, 0, stream>>>(aggB, xB, W1t, bl1, g1, b1, xaB, n);
    // layer 2
    k_agg<<<gg, 256, 0, stream>>>(xaB, off, cnt, csr, aggB, n);
    k_gemm<<<gg, 256, 0, stream>>>(aggB, xaB, W2t, bl2, g2, b2, xbB, n);
    // layer 3 (R17 form): project first, gather the 64-dim z (half the bytes)
    k_gemmW3<<<gg, 256, 0, stream>>>(xbB, W3c, Zb, Wb, n);
    k_aggpost3<<<gg, 256, 0, stream>>>(Zb, Wb, off, cnt, csr, bl3, gc, bc, yB, n);
    // classifier matvec
    k_mm<<<gg, 256, 0, stream>>>(yB, Wct, bcls, (float*)d_out, n);
}

// Round 20
// 194.762 us; speedup vs baseline: 1.1416x; 1.0648x over previous
//
#include <hip/hip_runtime.h>
#include <math.h>

// ---------------------------------------------------------------------------
// CellTypeGNN: 2x [SAGE(mean) -> LN -> GELU -> +res] -> SAGE -> GELU -> LN -> Linear
// N=50000, E=800000, D=128, DOUT(conv3)=64, classes=40.
// R19: exact R15 structure (verified best, 202us) + dispatch-count reduction:
//     k_cast + 3x k_wprep + k_wprepC merged into one role-split k_prep
//     (R15 vs R18 A/B showed per-dispatch ramp/drain ~5us is first-order).
//     Hot path unchanged: zero-atomic CSR sort build; k_agg gather (rooflined
//     ~92% of achievable for its bytes); k_gemm with global_load_lds staging
//     (linear LDS dest + pre-swizzled source) + fused LN/GELU/residual;
//     layer-3 gemm fuses classifier LN + matvec (Ys in LDS).
// ---------------------------------------------------------------------------

typedef __attribute__((ext_vector_type(8))) short bf16x8;
typedef __attribute__((ext_vector_type(4))) float f32x4;

#define AS1 __attribute__((address_space(1)))
#define AS3 __attribute__((address_space(3)))

#define NWG 256      // workgroups in hist/scat passes
#define NBK 196      // buckets: dst>>8 (196*256 = 50176 >= n)
#define CAP2 6144    // per-bucket sortC capacity (expect ~4082, sigma 64)

__device__ inline float gelu_f(float x) {
    // tanh-approx GELU: 0.5x(1+tanh(c(x+0.044715x^3))) = x*sigmoid(2c*u)
    float u = x * (1.0f + 0.044715f * x * x);
    return x / (1.0f + __expf(-1.5957691216057308f * u));
}

__device__ inline ushort f2b(float f) {  // fp32 -> bf16 RNE
    uint u = __float_as_uint(f);
    u += 0x7fffu + ((u >> 16) & 1u);
    return (ushort)(u >> 16);
}

__device__ inline float b2f(ushort h) { return __uint_as_float((uint)h << 16); }

// ---------------- CSR build: hist -> scan -> scatter -> bucket sort ----------

__global__ __launch_bounds__(256) void k_hist(const int* __restrict__ dst, int e,
                                              int* __restrict__ cnts) {
    __shared__ int h[NBK];
    const int tid = threadIdx.x;
    const int wg = blockIdx.x;
    for (int i = tid; i < NBK; i += 256) h[i] = 0;
    __syncthreads();
    const int ch = (e + NWG - 1) / NWG;
    const int lo = wg * ch;
    const int hi = min(e, lo + ch);
    for (int i = lo + tid; i < hi; i += 256) atomicAdd(&h[dst[i] >> 8], 1);
    __syncthreads();
    for (int i = tid; i < NBK; i += 256) cnts[i * NWG + wg] = h[i];
}

__global__ __launch_bounds__(256) void k_scanP1(const int* __restrict__ in,
                                                int* __restrict__ out,
                                                int* __restrict__ part, int m) {
    __shared__ int sm[256];
    const int tid = threadIdx.x;
    const int base = blockIdx.x * 1024 + tid * 4;
    int4 v = make_int4(0, 0, 0, 0);
    if (base + 3 < m) {
        v = *(const int4*)(in + base);
    } else {
        if (base + 0 < m) v.x = in[base + 0];
        if (base + 1 < m) v.y = in[base + 1];
        if (base + 2 < m) v.z = in[base + 2];
        if (base + 3 < m) v.w = in[base + 3];
    }
    int s = v.x + v.y + v.z + v.w;
    sm[tid] = s;
    __syncthreads();
#pragma unroll
    for (int d = 1; d < 256; d <<= 1) {
        int add = (tid >= d) ? sm[tid - d] : 0;
        __syncthreads();
        sm[tid] += add;
        __syncthreads();
    }
    int ex = (tid ? sm[tid - 1] : 0);
    if (base + 0 < m) out[base + 0] = ex;
    ex += v.x;
    if (base + 1 < m) out[base + 1] = ex;
    ex += v.y;
    if (base + 2 < m) out[base + 2] = ex;
    ex += v.z;
    if (base + 3 < m) out[base + 3] = ex;
    if (tid == 255) part[blockIdx.x] = sm[255];
}

__global__ __launch_bounds__(256) void k_scanP2(int* __restrict__ out,
                                                const int* __restrict__ part, int m) {
    const int tid = threadIdx.x;
    const int bid = blockIdx.x;
    const int lane = tid & 63;
    int s = 0;
    for (int j = lane; j < bid; j += 64) s += part[j];
#pragma unroll
    for (int d = 32; d > 0; d >>= 1) s += __shfl_xor(s, d);
    const int i0 = bid * 1024 + tid * 4;
#pragma unroll
    for (int j = 0; j < 4; ++j) {
        int i = i0 + j;
        if (i < m) out[i] += s;
    }
}

// scatter packed (src | local_dst<<16) to exact (wg,bucket) segment positions
__global__ __launch_bounds__(256) void k_scat(const int* __restrict__ src,
                                              const int* __restrict__ dst, int e,
                                              const int* __restrict__ bases,
                                              uint* __restrict__ pairs) {
    __shared__ int cur[NBK];
    const int tid = threadIdx.x;
    const int wg = blockIdx.x;
    for (int i = tid; i < NBK; i += 256) cur[i] = bases[i * NWG + wg];
    __syncthreads();
    const int ch = (e + NWG - 1) / NWG;
    const int lo = wg * ch;
    const int hi = min(e, lo + ch);
    for (int i = lo + tid; i < hi; i += 256) {
        int d = dst[i];
        int pos = atomicAdd(&cur[d >> 8], 1);
        pairs[pos] = (uint)src[i] | ((uint)(d & 255) << 16);
    }
}

// one workgroup per bucket: LDS counting sort of its compact segment
__global__ __launch_bounds__(256) void k_sortC(const uint* __restrict__ pairs,
                                               const int* __restrict__ bases, int e,
                                               int* __restrict__ csr, int* __restrict__ off,
                                               int* __restrict__ cntout, int n) {
    __shared__ int hist[256];
    __shared__ int curl[256];
    __shared__ int sm[256];
    __shared__ int buf[CAP2];
    const int bk = blockIdx.x;
    const int tid = threadIdx.x;
    const int start = bases[bk * NWG];
    const int end = (bk == NBK - 1) ? e : bases[(bk + 1) * NWG];
    int m = end - start;
    if (m > CAP2) m = CAP2;

    hist[tid] = 0;
    __syncthreads();
    for (int i = tid; i < m; i += 256) atomicAdd(&hist[(pairs[start + i] >> 16) & 255], 1);
    __syncthreads();
    int v = hist[tid];
    sm[tid] = v;
    __syncthreads();
#pragma unroll
    for (int d = 1; d < 256; d <<= 1) {
        int add = (tid >= d) ? sm[tid - d] : 0;
        __syncthreads();
        sm[tid] += add;
        __syncthreads();
    }
    int excl = sm[tid] - v;
    int node = (bk << 8) + tid;
    if (node < n) {
        off[node] = start + excl;
        cntout[node] = v;
    }
    curl[tid] = excl;
    __syncthreads();
    for (int i = tid; i < m; i += 256) {
        uint w = pairs[start + i];
        int pos = atomicAdd(&curl[(w >> 16) & 255], 1);
        buf[pos] = (int)(w & 0xffffu);
    }
    __syncthreads();
    for (int i = tid; i < m; i += 256) csr[start + i] = buf[i];
}

// ---------------- merged prep: cast x->bf16 + all weight packs ----------------
// blocks [0,2048): grid-stride float4 cast of x (nvec4 items)
// blocks [2048, 2048+336): weight packing, flat element space:
//   [0,32768)      W1t[c][k]: c<128, k<256; k<128?Wl1[k][c]:Wr1[k-128][c]
//   [32768,65536)  W2t same with Wl2/Wr2
//   [65536,81920)  W3t[c][k]: c<64,  k<256; k<128?Wl3[k][c]:Wr3[k-128][c]
//   [81920,86016)  Wct[c][k]: c<64,  k<64;  c<40?Wc[k][c]:0

__global__ __launch_bounds__(256) void k_prep(
    const float* __restrict__ x, ushort* __restrict__ xB, int nvec4,
    const float* __restrict__ Wl1, const float* __restrict__ Wr1, ushort* __restrict__ W1t,
    const float* __restrict__ Wl2, const float* __restrict__ Wr2, ushort* __restrict__ W2t,
    const float* __restrict__ Wl3, const float* __restrict__ Wr3, ushort* __restrict__ W3t,
    const float* __restrict__ Wc, ushort* __restrict__ Wct) {
    const int b = blockIdx.x;
    if (b < 2048) {
        int t = b * 256 + threadIdx.x;
        for (int i = t; i < nvec4; i += 2048 * 256) {
            float4 v = ((const float4*)x)[i];
            ushort4 o;
            o.x = f2b(v.x);
            o.y = f2b(v.y);
            o.z = f2b(v.z);
            o.w = f2b(v.w);
            ((ushort4*)xB)[i] = o;
        }
    } else {
        int t = (b - 2048) * 256 + threadIdx.x;
        if (t < 32768) {
            int c = t >> 8, k = t & 255;
            float v = (k < 128) ? Wl1[(size_t)k * 128 + c] : Wr1[(size_t)(k - 128) * 128 + c];
            W1t[t] = f2b(v);
        } else if (t < 65536) {
            int tt = t - 32768;
            int c = tt >> 8, k = tt & 255;
            float v = (k < 128) ? Wl2[(size_t)k * 128 + c] : Wr2[(size_t)(k - 128) * 128 + c];
            W2t[tt] = f2b(v);
        } else if (t < 81920) {
            int tt = t - 65536;
            int c = tt >> 8, k = tt & 255;
            float v = (k < 128) ? Wl3[(size_t)k * 64 + c] : Wr3[(size_t)(k - 128) * 64 + c];
            W3t[tt] = f2b(v);
        } else if (t < 86016) {
            int tt = t - 81920;
            int c = tt >> 6, k = tt & 63;
            float v = (c < 40) ? Wc[k * 40 + c] : 0.f;
            Wct[tt] = f2b(v);
        }
    }
}

// ---------------- mean aggregation (bf16 in/out, fp32 accumulate) ----------------

__global__ __launch_bounds__(256) void k_agg(const ushort* __restrict__ X,
                                             const int* __restrict__ off,
                                             const int* __restrict__ cnt,
                                             const int* __restrict__ csr,
                                             ushort* __restrict__ agg, int n) {
    const int wave = threadIdx.x >> 6;
    const int lane = threadIdx.x & 63;
    const int base = blockIdx.x * 32 + wave * 8;
#pragma unroll 1
    for (int j = 0; j < 8; ++j) {
        const int i = base + j;
        if (i >= n) return;
        int s0 = off[i];
        int deg = cnt[i];
        int c = 0;
        if (lane < deg) c = csr[s0 + lane];
        float a0 = 0.f, a1 = 0.f;
        const int dcap = deg < 64 ? deg : 64;
        int t = 0;
        for (; t + 3 < dcap; t += 4) {
            int i0 = __shfl(c, t), i1 = __shfl(c, t + 1);
            int i2 = __shfl(c, t + 2), i3 = __shfl(c, t + 3);
            uint u0 = *((const uint*)(X + (size_t)i0 * 128) + lane);
            uint u1 = *((const uint*)(X + (size_t)i1 * 128) + lane);
            uint u2 = *((const uint*)(X + (size_t)i2 * 128) + lane);
            uint u3 = *((const uint*)(X + (size_t)i3 * 128) + lane);
            a0 += __uint_as_float(u0 << 16) + __uint_as_float(u1 << 16) +
                  __uint_as_float(u2 << 16) + __uint_as_float(u3 << 16);
            a1 += __uint_as_float(u0 & 0xffff0000u) + __uint_as_float(u1 & 0xffff0000u) +
                  __uint_as_float(u2 & 0xffff0000u) + __uint_as_float(u3 & 0xffff0000u);
        }
        for (; t < dcap; ++t) {
            uint u0 = *((const uint*)(X + (size_t)__shfl(c, t) * 128) + lane);
            a0 += __uint_as_float(u0 << 16);
            a1 += __uint_as_float(u0 & 0xffff0000u);
        }
        for (int tt = s0 + 64; tt < s0 + deg; ++tt) {  // rare deg>64 tail
            uint u0 = *((const uint*)(X + (size_t)csr[tt] * 128) + lane);
            a0 += __uint_as_float(u0 << 16);
            a1 += __uint_as_float(u0 & 0xffff0000u);
        }
        float inv = 1.0f / (float)(deg > 1 ? deg : 1);
        uint pk = (uint)f2b(a0 * inv) | ((uint)f2b(a1 * inv) << 16);
        *((uint*)(agg + (size_t)i * 128) + lane) = pk;
    }
}

// ---------------- MFMA SAGE GEMM (global_load_lds staging; R15 verified) ------
// Block = 32 rows x DOUT cols, 4 waves. A = [Agg row(256B) | Xb row(256B)]
// = 512B/row in LDS. Staging: 4x global_load_lds width=16 per wave. LDS dest
// LINEAR (base + lane*16); global source pre-swizzled per-lane:
// srcb = slot*16 ^ ((row&7)<<4) (bijective within each 256B half). Reads
// apply the same XOR -> conflict-free ds_read_b128.
// EPI 1: LN+GELU+residual(Xb from LDS) -> bf16 [n][128].
// EPI 3: GELU -> LN -> y to swizzled LDS -> matvec y@Wct^T + bcls -> f32 out.

template <int DOUT, int EPI>
__global__ __launch_bounds__(256) void k_gemm(
    const ushort* __restrict__ Agg, const ushort* __restrict__ Xb,
    const ushort* __restrict__ Wt, const float* __restrict__ bias,
    const float* __restrict__ g, const float* __restrict__ b,
    ushort* __restrict__ OutB,          // EPI1: bf16 [n][128]
    const ushort* __restrict__ Wct,     // EPI3: [64][64] bf16
    const float* __restrict__ bcls,     // EPI3
    float* __restrict__ OutF,           // EPI3: f32 [n][40]
    int n) {
    constexpr int CT = DOUT / 64;  // 2 (DOUT=128) or 1 (64)
    const int tid = threadIdx.x;
    const int wave = tid >> 6;
    const int lane = tid & 63;
    const int l16 = lane & 15;
    const int g4 = lane >> 4;
    const int row0 = blockIdx.x * 32;

    __shared__ __align__(16) ushort As[32 * 256];  // 16 KB linear [row][512B]
    __shared__ float sP[32][4];
    __shared__ float qP[32][4];
    __shared__ __align__(16) ushort Ys[EPI == 3 ? 32 * 64 : 1];  // 4KB (EPI3)

    // ---- stage A: direct global->LDS DMA, pre-swizzled per-lane source ----
    {
        const int slot = lane & 31;
#pragma unroll
        for (int i = 0; i < 4; ++i) {
            const int rr = (wave * 4 + i) * 2 + (lane >> 5);  // 0..31
            int gr = row0 + rr;
            if (gr > n - 1) gr = n - 1;
            const int srcb = (slot * 16) ^ ((rr & 7) << 4);
            const char* gp = (srcb < 256)
                                 ? (const char*)Agg + (size_t)gr * 256 + srcb
                                 : (const char*)Xb + (size_t)gr * 256 + (srcb - 256);
            char* lp = (char*)As + (wave * 4 + i) * 1024;  // wave-uniform base
            __builtin_amdgcn_global_load_lds((const AS1 void*)gp, (AS3 void*)lp, 16, 0, 0);
        }
    }

    int colv[CT];
#pragma unroll
    for (int ct = 0; ct < CT; ++ct) colv[ct] = (wave * CT + ct) * 16 + l16;

    // ---- B fragments from global (L2-hot; overlap with DMA) ----
    bf16x8 bfr[CT][8];
#pragma unroll
    for (int ct = 0; ct < CT; ++ct) {
        const ushort* wp = Wt + (size_t)colv[ct] * 256 + g4 * 8;
#pragma unroll
        for (int ks = 0; ks < 8; ++ks) bfr[ct][ks] = *(const bf16x8*)(wp + ks * 32);
    }
    float biasv[CT], gv[CT], bbv[CT];
#pragma unroll
    for (int ct = 0; ct < CT; ++ct) {
        biasv[ct] = bias[colv[ct]];
        gv[ct] = g[colv[ct]];
        bbv[ct] = b[colv[ct]];
    }

    __syncthreads();  // drains vmcnt incl. global_load_lds

    // ---- MFMA: A-frags from LDS (swizzled read), B from registers ----
    f32x4 acc[2][CT];
#pragma unroll
    for (int rt = 0; rt < 2; ++rt)
#pragma unroll
        for (int ct = 0; ct < CT; ++ct) {
            acc[rt][ct][0] = 0.f;
            acc[rt][ct][1] = 0.f;
            acc[rt][ct][2] = 0.f;
            acc[rt][ct][3] = 0.f;
        }
#pragma unroll
    for (int ks = 0; ks < 8; ++ks) {
        bf16x8 a[2];
#pragma unroll
        for (int rt = 0; rt < 2; ++rt) {
            const int row = rt * 16 + l16;
            a[rt] = *(const bf16x8*)((const char*)As + row * 512 +
                                     ((ks * 64 + g4 * 16) ^ ((row & 7) << 4)));
        }
#pragma unroll
        for (int rt = 0; rt < 2; ++rt)
#pragma unroll
            for (int ct = 0; ct < CT; ++ct)
                acc[rt][ct] = __builtin_amdgcn_mfma_f32_16x16x32_bf16(a[rt], bfr[ct][ks],
                                                                     acc[rt][ct], 0, 0, 0);
    }

    // ---- epilogue: cross-wave LN via LDS partials ----
    float v[2][4][CT];
    float sv[2][4], qv[2][4];
#pragma unroll
    for (int rt = 0; rt < 2; ++rt)
#pragma unroll
        for (int reg = 0; reg < 4; ++reg) {
            float s = 0.f, q = 0.f;
#pragma unroll
            for (int ct = 0; ct < CT; ++ct) {
                float tv = acc[rt][ct][reg] + biasv[ct];
                if (EPI == 3) tv = gelu_f(tv);  // GELU BEFORE LN (conv3 path)
                v[rt][reg][ct] = tv;
                s += tv;
                q += tv * tv;
            }
            sv[rt][reg] = s;
            qv[rt][reg] = q;
        }
#pragma unroll
    for (int m = 1; m < 16; m <<= 1)
#pragma unroll
        for (int rt = 0; rt < 2; ++rt)
#pragma unroll
            for (int reg = 0; reg < 4; ++reg) {
                sv[rt][reg] += __shfl_xor(sv[rt][reg], m);
                qv[rt][reg] += __shfl_xor(qv[rt][reg], m);
            }
    if (l16 == 0) {
#pragma unroll
        for (int rt = 0; rt < 2; ++rt)
#pragma unroll
            for (int reg = 0; reg < 4; ++reg) {
                int rib = rt * 16 + g4 * 4 + reg;
                sP[rib][wave] = sv[rt][reg];
                qP[rib][wave] = qv[rt][reg];
            }
    }
    __syncthreads();

#pragma unroll
    for (int rt = 0; rt < 2; ++rt) {
#pragma unroll
        for (int reg = 0; reg < 4; ++reg) {
            int rib = rt * 16 + g4 * 4 + reg;
            float s = sP[rib][0] + sP[rib][1] + sP[rib][2] + sP[rib][3];
            float q = qP[rib][0] + qP[rib][1] + qP[rib][2] + qP[rib][3];
            float mu = s * (1.0f / (float)DOUT);
            float var = q * (1.0f / (float)DOUT) - mu * mu;
            float rs = rsqrtf(fmaxf(var, 0.f) + 1e-5f);
            int r = row0 + rib;
#pragma unroll
            for (int ct = 0; ct < CT; ++ct) {
                float y = (v[rt][reg][ct] - mu) * rs * gv[ct] + bbv[ct];
                if (EPI == 1) {
                    if (r < n) {
                        // residual = Xb row (LDS k = 128+col, swizzled)
                        ushort rh = *(const ushort*)((const char*)As + rib * 512 +
                                                     ((256 + 2 * colv[ct]) ^ ((rib & 7) << 4)));
                        y = gelu_f(y) + b2f(rh);
                        OutB[(size_t)r * DOUT + colv[ct]] = f2b(y);
                    }
                } else {
                    // stash LN'd y into swizzled LDS for the fused matvec
                    *(ushort*)((char*)Ys + rib * 128 +
                               ((2 * colv[ct]) ^ ((rib & 7) << 4))) = f2b(y);
                }
            }
        }
    }

    if (EPI == 3) {
        __syncthreads();
        // fused classifier matvec: Out = Ys @ Wct^T + bcls (4 MFMA, no shfl)
        const int col = wave * 16 + l16;
        bf16x8 b2r[2];
#pragma unroll
        for (int ks = 0; ks < 2; ++ks)
            b2r[ks] = *(const bf16x8*)(Wct + (size_t)col * 64 + ks * 32 + g4 * 8);
        f32x4 acc2[2];
#pragma unroll
        for (int rt = 0; rt < 2; ++rt) {
            acc2[rt][0] = 0.f;
            acc2[rt][1] = 0.f;
            acc2[rt][2] = 0.f;
            acc2[rt][3] = 0.f;
        }
#pragma unroll
        for (int ks = 0; ks < 2; ++ks)
#pragma unroll
            for (int rt = 0; rt < 2; ++rt) {
                const int row = rt * 16 + l16;
                bf16x8 a = *(const bf16x8*)((const char*)Ys + row * 128 +
                                            ((ks * 64 + g4 * 16) ^ ((row & 7) << 4)));
                acc2[rt] = __builtin_amdgcn_mfma_f32_16x16x32_bf16(a, b2r[ks], acc2[rt], 0, 0, 0);
            }
        const float bcv = (col < 40) ? bcls[col] : 0.f;
#pragma unroll
        for (int rt = 0; rt < 2; ++rt)
#pragma unroll
            for (int reg = 0; reg < 4; ++reg) {
                int r = row0 + rt * 16 + g4 * 4 + reg;
                if (r < n && col < 40) OutF[(size_t)r * 40 + col] = acc2[rt][reg] + bcv;
            }
    }
}

// ---------------------------------------------------------------------------

extern "C" void kernel_launch(void* const* d_in, const int* in_sizes, int n_in,
                              void* d_out, int out_size, void* d_ws, size_t ws_size,
                              hipStream_t stream) {
    const float* x   = (const float*)d_in[0];
    const int* ei    = (const int*)d_in[1];
    const float* Wl1 = (const float*)d_in[2];
    const float* bl1 = (const float*)d_in[3];
    const float* Wr1 = (const float*)d_in[4];
    const float* g1  = (const float*)d_in[5];
    const float* b1  = (const float*)d_in[6];
    const float* Wl2 = (const float*)d_in[7];
    const float* bl2 = (const float*)d_in[8];
    const float* Wr2 = (const float*)d_in[9];
    const float* g2  = (const float*)d_in[10];
    const float* b2  = (const float*)d_in[11];
    const float* Wl3 = (const float*)d_in[12];
    const float* bl3 = (const float*)d_in[13];
    const float* Wr3 = (const float*)d_in[14];
    const float* gc  = (const float*)d_in[15];
    const float* bc  = (const float*)d_in[16];
    const float* Wc  = (const float*)d_in[17];
    const float* bcls= (const float*)d_in[18];

    const int n = in_sizes[0] / 128;  // 50000
    const int e = in_sizes[1] / 2;    // 800000
    const int* src = ei;
    const int* dst = ei + e;

    char* w = (char*)d_ws;
    size_t o = 0;
    auto alloc = [&](size_t bytes) -> char* {
        char* p = w + o;
        o = (o + bytes + 511) & ~(size_t)511;
        return p;
    };
    int* cnts    = (int*)alloc((size_t)NBK * NWG * 4);
    int* bases   = (int*)alloc((size_t)NBK * NWG * 4);
    int* part    = (int*)alloc(256 * 4);
    uint* pairs  = (uint*)alloc((size_t)e * 4);
    int* csr     = (int*)alloc((size_t)e * 4);
    int* off     = (int*)alloc((size_t)n * 4);
    int* cnt     = (int*)alloc((size_t)n * 4);
    ushort* xB   = (ushort*)alloc((size_t)n * 128 * 2);
    ushort* aggB = (ushort*)alloc((size_t)n * 128 * 2);
    ushort* xaB  = (ushort*)alloc((size_t)n * 128 * 2);
    ushort* xbB  = (ushort*)alloc((size_t)n * 128 * 2);
    ushort* W1t  = (ushort*)alloc((size_t)128 * 256 * 2);
    ushort* W2t  = (ushort*)alloc((size_t)128 * 256 * 2);
    ushort* W3t  = (ushort*)alloc((size_t)64 * 256 * 2);
    ushort* Wct  = (ushort*)alloc((size_t)64 * 64 * 2);
    (void)ws_size;

    // CSR build: hist -> scan -> scatter -> per-bucket sort (no global atomics)
    const int m = NBK * NWG;              // 50176
    const int sblk = (m + 1023) / 1024;   // 49
    k_hist<<<NWG, 256, 0, stream>>>(dst, e, cnts);
    k_scanP1<<<sblk, 256, 0, stream>>>(cnts, bases, part, m);
    k_scanP2<<<sblk, 256, 0, stream>>>(bases, part, m);
    k_scat<<<NWG, 256, 0, stream>>>(src, dst, e, bases, pairs);
    k_sortC<<<NBK, 256, 0, stream>>>(pairs, bases, e, csr, off, cnt, n);

    // merged prep: cast + all 4 weight packs in one dispatch
    k_prep<<<2048 + 336, 256, 0, stream>>>(x, xB, n * 128 / 4, Wl1, Wr1, W1t,
                                           Wl2, Wr2, W2t, Wl3, Wr3, W3t, Wc, Wct);

    const int gg = (n + 31) / 32;  // shared grid: agg + gemm

    // block 1
    k_agg<<<gg, 256, 0, stream>>>(xB, off, cnt, csr, aggB, n);
    k_gemm<128, 1><<<gg, 256, 0, stream>>>(aggB, xB, W1t, bl1, g1, b1, xaB,
                                           nullptr, nullptr, nullptr, n);
    // block 2
    k_agg<<<gg, 256, 0, stream>>>(xaB, off, cnt, csr, aggB, n);
    k_gemm<128, 1><<<gg, 256, 0, stream>>>(aggB, xaB, W2t, bl2, g2, b2, xbB,
                                           nullptr, nullptr, nullptr, n);
    // conv_out + GELU + classifier LN + classifier matvec (all fused)
    k_agg<<<gg, 256, 0, stream>>>(xbB, off, cnt, csr, aggB, n);
    k_gemm<64, 3><<<gg, 256, 0, stream>>>(aggB, xbB, W3t, bl3, gc, bc, nullptr,
                                          Wct, bcls, (float*)d_out, n);
}

// Round 21
// 191.954 us; speedup vs baseline: 1.1583x; 1.0146x over previous
//
#include <hip/hip_runtime.h>
#include <math.h>

// ---------------------------------------------------------------------------
// CellTypeGNN: 2x [SAGE(mean) -> LN -> GELU -> +res] -> SAGE -> GELU -> LN -> Linear
// N=50000, E=800000, D=128, DOUT(conv3)=64, classes=40.
// R20: R19 + fold k_hist into k_prep (role-split grid: [0,256) hist,
//     [256,2304) cast, [2304,2640) weight packs). Dispatch-merge is the
//     validated lever (R19: -7us from 4 fewer dispatches). Hot path unchanged:
//     zero-atomic CSR sort; rooflined k_agg gather; k_gemm with
//     global_load_lds staging + fused LN/GELU/residual; layer-3 gemm fuses
//     classifier LN + matvec.
// ---------------------------------------------------------------------------

typedef __attribute__((ext_vector_type(8))) short bf16x8;
typedef __attribute__((ext_vector_type(4))) float f32x4;

#define AS1 __attribute__((address_space(1)))
#define AS3 __attribute__((address_space(3)))

#define NWG 256      // workgroups in hist/scat passes
#define NBK 196      // buckets: dst>>8 (196*256 = 50176 >= n)
#define CAP2 6144    // per-bucket sortC capacity (expect ~4082, sigma 64)

__device__ inline float gelu_f(float x) {
    // tanh-approx GELU: 0.5x(1+tanh(c(x+0.044715x^3))) = x*sigmoid(2c*u)
    float u = x * (1.0f + 0.044715f * x * x);
    return x / (1.0f + __expf(-1.5957691216057308f * u));
}

__device__ inline ushort f2b(float f) {  // fp32 -> bf16 RNE
    uint u = __float_as_uint(f);
    u += 0x7fffu + ((u >> 16) & 1u);
    return (ushort)(u >> 16);
}

__device__ inline float b2f(ushort h) { return __uint_as_float((uint)h << 16); }

// ---------------- merged prep: hist + cast + weight packs --------------------
// blocks [0,NWG): per-WG LDS histogram of dst>>8 -> cnts[bucket][wg]
// blocks [NWG, NWG+2048): grid-stride float4 cast of x
// blocks [NWG+2048, NWG+2048+336): weight packing (flat element space)

__global__ __launch_bounds__(256) void k_prep(
    const int* __restrict__ dst, int e, int* __restrict__ cnts,
    const float* __restrict__ x, ushort* __restrict__ xB, int nvec4,
    const float* __restrict__ Wl1, const float* __restrict__ Wr1, ushort* __restrict__ W1t,
    const float* __restrict__ Wl2, const float* __restrict__ Wr2, ushort* __restrict__ W2t,
    const float* __restrict__ Wl3, const float* __restrict__ Wr3, ushort* __restrict__ W3t,
    const float* __restrict__ Wc, ushort* __restrict__ Wct) {
    __shared__ int h[NBK];
    const int b = blockIdx.x;
    if (b < NWG) {
        const int tid = threadIdx.x;
        for (int i = tid; i < NBK; i += 256) h[i] = 0;
        __syncthreads();
        const int ch = (e + NWG - 1) / NWG;
        const int lo = b * ch;
        const int hi = min(e, lo + ch);
        for (int i = lo + tid; i < hi; i += 256) atomicAdd(&h[dst[i] >> 8], 1);
        __syncthreads();
        for (int i = tid; i < NBK; i += 256) cnts[i * NWG + b] = h[i];
    } else if (b < NWG + 2048) {
        int t = (b - NWG) * 256 + threadIdx.x;
        for (int i = t; i < nvec4; i += 2048 * 256) {
            float4 v = ((const float4*)x)[i];
            ushort4 o;
            o.x = f2b(v.x);
            o.y = f2b(v.y);
            o.z = f2b(v.z);
            o.w = f2b(v.w);
            ((ushort4*)xB)[i] = o;
        }
    } else {
        int t = (b - NWG - 2048) * 256 + threadIdx.x;
        if (t < 32768) {
            int c = t >> 8, k = t & 255;
            float v = (k < 128) ? Wl1[(size_t)k * 128 + c] : Wr1[(size_t)(k - 128) * 128 + c];
            W1t[t] = f2b(v);
        } else if (t < 65536) {
            int tt = t - 32768;
            int c = tt >> 8, k = tt & 255;
            float v = (k < 128) ? Wl2[(size_t)k * 128 + c] : Wr2[(size_t)(k - 128) * 128 + c];
            W2t[tt] = f2b(v);
        } else if (t < 81920) {
            int tt = t - 65536;
            int c = tt >> 8, k = tt & 255;
            float v = (k < 128) ? Wl3[(size_t)k * 64 + c] : Wr3[(size_t)(k - 128) * 64 + c];
            W3t[tt] = f2b(v);
        } else if (t < 86016) {
            int tt = t - 81920;
            int c = tt >> 6, k = tt & 63;
            float v = (c < 40) ? Wc[k * 40 + c] : 0.f;
            Wct[tt] = f2b(v);
        }
    }
}

// ---------------- CSR build: scan -> scatter -> bucket sort ------------------

__global__ __launch_bounds__(256) void k_scanP1(const int* __restrict__ in,
                                                int* __restrict__ out,
                                                int* __restrict__ part, int m) {
    __shared__ int sm[256];
    const int tid = threadIdx.x;
    const int base = blockIdx.x * 1024 + tid * 4;
    int4 v = make_int4(0, 0, 0, 0);
    if (base + 3 < m) {
        v = *(const int4*)(in + base);
    } else {
        if (base + 0 < m) v.x = in[base + 0];
        if (base + 1 < m) v.y = in[base + 1];
        if (base + 2 < m) v.z = in[base + 2];
        if (base + 3 < m) v.w = in[base + 3];
    }
    int s = v.x + v.y + v.z + v.w;
    sm[tid] = s;
    __syncthreads();
#pragma unroll
    for (int d = 1; d < 256; d <<= 1) {
        int add = (tid >= d) ? sm[tid - d] : 0;
        __syncthreads();
        sm[tid] += add;
        __syncthreads();
    }
    int ex = (tid ? sm[tid - 1] : 0);
    if (base + 0 < m) out[base + 0] = ex;
    ex += v.x;
    if (base + 1 < m) out[base + 1] = ex;
    ex += v.y;
    if (base + 2 < m) out[base + 2] = ex;
    ex += v.z;
    if (base + 3 < m) out[base + 3] = ex;
    if (tid == 255) part[blockIdx.x] = sm[255];
}

__global__ __launch_bounds__(256) void k_scanP2(int* __restrict__ out,
                                                const int* __restrict__ part, int m) {
    const int tid = threadIdx.x;
    const int bid = blockIdx.x;
    const int lane = tid & 63;
    int s = 0;
    for (int j = lane; j < bid; j += 64) s += part[j];
#pragma unroll
    for (int d = 32; d > 0; d >>= 1) s += __shfl_xor(s, d);
    const int i0 = bid * 1024 + tid * 4;
#pragma unroll
    for (int j = 0; j < 4; ++j) {
        int i = i0 + j;
        if (i < m) out[i] += s;
    }
}

// scatter packed (src | local_dst<<16) to exact (wg,bucket) segment positions
__global__ __launch_bounds__(256) void k_scat(const int* __restrict__ src,
                                              const int* __restrict__ dst, int e,
                                              const int* __restrict__ bases,
                                              uint* __restrict__ pairs) {
    __shared__ int cur[NBK];
    const int tid = threadIdx.x;
    const int wg = blockIdx.x;
    for (int i = tid; i < NBK; i += 256) cur[i] = bases[i * NWG + wg];
    __syncthreads();
    const int ch = (e + NWG - 1) / NWG;
    const int lo = wg * ch;
    const int hi = min(e, lo + ch);
    for (int i = lo + tid; i < hi; i += 256) {
        int d = dst[i];
        int pos = atomicAdd(&cur[d >> 8], 1);
        pairs[pos] = (uint)src[i] | ((uint)(d & 255) << 16);
    }
}

// one workgroup per bucket: LDS counting sort of its compact segment
__global__ __launch_bounds__(256) void k_sortC(const uint* __restrict__ pairs,
                                               const int* __restrict__ bases, int e,
                                               int* __restrict__ csr, int* __restrict__ off,
                                               int* __restrict__ cntout, int n) {
    __shared__ int hist[256];
    __shared__ int curl[256];
    __shared__ int sm[256];
    __shared__ int buf[CAP2];
    const int bk = blockIdx.x;
    const int tid = threadIdx.x;
    const int start = bases[bk * NWG];
    const int end = (bk == NBK - 1) ? e : bases[(bk + 1) * NWG];
    int m = end - start;
    if (m > CAP2) m = CAP2;

    hist[tid] = 0;
    __syncthreads();
    for (int i = tid; i < m; i += 256) atomicAdd(&hist[(pairs[start + i] >> 16) & 255], 1);
    __syncthreads();
    int v = hist[tid];
    sm[tid] = v;
    __syncthreads();
#pragma unroll
    for (int d = 1; d < 256; d <<= 1) {
        int add = (tid >= d) ? sm[tid - d] : 0;
        __syncthreads();
        sm[tid] += add;
        __syncthreads();
    }
    int excl = sm[tid] - v;
    int node = (bk << 8) + tid;
    if (node < n) {
        off[node] = start + excl;
        cntout[node] = v;
    }
    curl[tid] = excl;
    __syncthreads();
    for (int i = tid; i < m; i += 256) {
        uint w = pairs[start + i];
        int pos = atomicAdd(&curl[(w >> 16) & 255], 1);
        buf[pos] = (int)(w & 0xffffu);
    }
    __syncthreads();
    for (int i = tid; i < m; i += 256) csr[start + i] = buf[i];
}

// ---------------- mean aggregation (bf16 in/out, fp32 accumulate) ----------------

__global__ __launch_bounds__(256) void k_agg(const ushort* __restrict__ X,
                                             const int* __restrict__ off,
                                             const int* __restrict__ cnt,
                                             const int* __restrict__ csr,
                                             ushort* __restrict__ agg, int n) {
    const int wave = threadIdx.x >> 6;
    const int lane = threadIdx.x & 63;
    const int base = blockIdx.x * 32 + wave * 8;
#pragma unroll 1
    for (int j = 0; j < 8; ++j) {
        const int i = base + j;
        if (i >= n) return;
        int s0 = off[i];
        int deg = cnt[i];
        int c = 0;
        if (lane < deg) c = csr[s0 + lane];
        float a0 = 0.f, a1 = 0.f;
        const int dcap = deg < 64 ? deg : 64;
        int t = 0;
        for (; t + 3 < dcap; t += 4) {
            int i0 = __shfl(c, t), i1 = __shfl(c, t + 1);
            int i2 = __shfl(c, t + 2), i3 = __shfl(c, t + 3);
            uint u0 = *((const uint*)(X + (size_t)i0 * 128) + lane);
            uint u1 = *((const uint*)(X + (size_t)i1 * 128) + lane);
            uint u2 = *((const uint*)(X + (size_t)i2 * 128) + lane);
            uint u3 = *((const uint*)(X + (size_t)i3 * 128) + lane);
            a0 += __uint_as_float(u0 << 16) + __uint_as_float(u1 << 16) +
                  __uint_as_float(u2 << 16) + __uint_as_float(u3 << 16);
            a1 += __uint_as_float(u0 & 0xffff0000u) + __uint_as_float(u1 & 0xffff0000u) +
                  __uint_as_float(u2 & 0xffff0000u) + __uint_as_float(u3 & 0xffff0000u);
        }
        for (; t < dcap; ++t) {
            uint u0 = *((const uint*)(X + (size_t)__shfl(c, t) * 128) + lane);
            a0 += __uint_as_float(u0 << 16);
            a1 += __uint_as_float(u0 & 0xffff0000u);
        }
        for (int tt = s0 + 64; tt < s0 + deg; ++tt) {  // rare deg>64 tail
            uint u0 = *((const uint*)(X + (size_t)csr[tt] * 128) + lane);
            a0 += __uint_as_float(u0 << 16);
            a1 += __uint_as_float(u0 & 0xffff0000u);
        }
        float inv = 1.0f / (float)(deg > 1 ? deg : 1);
        uint pk = (uint)f2b(a0 * inv) | ((uint)f2b(a1 * inv) << 16);
        *((uint*)(agg + (size_t)i * 128) + lane) = pk;
    }
}

// ---------------- MFMA SAGE GEMM (global_load_lds staging) -------------------
// Block = 32 rows x DOUT cols, 4 waves. A = [Agg row(256B) | Xb row(256B)]
// = 512B/row in LDS. Staging: 4x global_load_lds width=16 per wave. LDS dest
// LINEAR (base + lane*16); global source pre-swizzled per-lane:
// srcb = slot*16 ^ ((row&7)<<4) (bijective within each 256B half). Reads
// apply the same XOR -> conflict-free ds_read_b128.
// EPI 1: LN+GELU+residual(Xb from LDS) -> bf16 [n][128].
// EPI 3: GELU -> LN -> y to swizzled LDS -> matvec y@Wct^T + bcls -> f32 out.

template <int DOUT, int EPI>
__global__ __launch_bounds__(256) void k_gemm(
    const ushort* __restrict__ Agg, const ushort* __restrict__ Xb,
    const ushort* __restrict__ Wt, const float* __restrict__ bias,
    const float* __restrict__ g, const float* __restrict__ b,
    ushort* __restrict__ OutB,          // EPI1: bf16 [n][128]
    const ushort* __restrict__ Wct,     // EPI3: [64][64] bf16
    const float* __restrict__ bcls,     // EPI3
    float* __restrict__ OutF,           // EPI3: f32 [n][40]
    int n) {
    constexpr int CT = DOUT / 64;  // 2 (DOUT=128) or 1 (64)
    const int tid = threadIdx.x;
    const int wave = tid >> 6;
    const int lane = tid & 63;
    const int l16 = lane & 15;
    const int g4 = lane >> 4;
    const int row0 = blockIdx.x * 32;

    __shared__ __align__(16) ushort As[32 * 256];  // 16 KB linear [row][512B]
    __shared__ float sP[32][4];
    __shared__ float qP[32][4];
    __shared__ __align__(16) ushort Ys[EPI == 3 ? 32 * 64 : 1];  // 4KB (EPI3)

    // ---- stage A: direct global->LDS DMA, pre-swizzled per-lane source ----
    {
        const int slot = lane & 31;
#pragma unroll
        for (int i = 0; i < 4; ++i) {
            const int rr = (wave * 4 + i) * 2 + (lane >> 5);  // 0..31
            int gr = row0 + rr;
            if (gr > n - 1) gr = n - 1;
            const int srcb = (slot * 16) ^ ((rr & 7) << 4);
            const char* gp = (srcb < 256)
                                 ? (const char*)Agg + (size_t)gr * 256 + srcb
                                 : (const char*)Xb + (size_t)gr * 256 + (srcb - 256);
            char* lp = (char*)As + (wave * 4 + i) * 1024;  // wave-uniform base
            __builtin_amdgcn_global_load_lds((const AS1 void*)gp, (AS3 void*)lp, 16, 0, 0);
        }
    }

    int colv[CT];
#pragma unroll
    for (int ct = 0; ct < CT; ++ct) colv[ct] = (wave * CT + ct) * 16 + l16;

    // ---- B fragments from global (L2-hot; overlap with DMA) ----
    bf16x8 bfr[CT][8];
#pragma unroll
    for (int ct = 0; ct < CT; ++ct) {
        const ushort* wp = Wt + (size_t)colv[ct] * 256 + g4 * 8;
#pragma unroll
        for (int ks = 0; ks < 8; ++ks) bfr[ct][ks] = *(const bf16x8*)(wp + ks * 32);
    }
    float biasv[CT], gv[CT], bbv[CT];
#pragma unroll
    for (int ct = 0; ct < CT; ++ct) {
        biasv[ct] = bias[colv[ct]];
        gv[ct] = g[colv[ct]];
        bbv[ct] = b[colv[ct]];
    }

    __syncthreads();  // drains vmcnt incl. global_load_lds

    // ---- MFMA: A-frags from LDS (swizzled read), B from registers ----
    f32x4 acc[2][CT];
#pragma unroll
    for (int rt = 0; rt < 2; ++rt)
#pragma unroll
        for (int ct = 0; ct < CT; ++ct) {
            acc[rt][ct][0] = 0.f;
            acc[rt][ct][1] = 0.f;
            acc[rt][ct][2] = 0.f;
            acc[rt][ct][3] = 0.f;
        }
#pragma unroll
    for (int ks = 0; ks < 8; ++ks) {
        bf16x8 a[2];
#pragma unroll
        for (int rt = 0; rt < 2; ++rt) {
            const int row = rt * 16 + l16;
            a[rt] = *(const bf16x8*)((const char*)As + row * 512 +
                                     ((ks * 64 + g4 * 16) ^ ((row & 7) << 4)));
        }
#pragma unroll
        for (int rt = 0; rt < 2; ++rt)
#pragma unroll
            for (int ct = 0; ct < CT; ++ct)
                acc[rt][ct] = __builtin_amdgcn_mfma_f32_16x16x32_bf16(a[rt], bfr[ct][ks],
                                                                     acc[rt][ct], 0, 0, 0);
    }

    // ---- epilogue: cross-wave LN via LDS partials ----
    float v[2][4][CT];
    float sv[2][4], qv[2][4];
#pragma unroll
    for (int rt = 0; rt < 2; ++rt)
#pragma unroll
        for (int reg = 0; reg < 4; ++reg) {
            float s = 0.f, q = 0.f;
#pragma unroll
            for (int ct = 0; ct < CT; ++ct) {
                float tv = acc[rt][ct][reg] + biasv[ct];
                if (EPI == 3) tv = gelu_f(tv);  // GELU BEFORE LN (conv3 path)
                v[rt][reg][ct] = tv;
                s += tv;
                q += tv * tv;
            }
            sv[rt][reg] = s;
            qv[rt][reg] = q;
        }
#pragma unroll
    for (int m = 1; m < 16; m <<= 1)
#pragma unroll
        for (int rt = 0; rt < 2; ++rt)
#pragma unroll
            for (int reg = 0; reg < 4; ++reg) {
                sv[rt][reg] += __shfl_xor(sv[rt][reg], m);
                qv[rt][reg] += __shfl_xor(qv[rt][reg], m);
            }
    if (l16 == 0) {
#pragma unroll
        for (int rt = 0; rt < 2; ++rt)
#pragma unroll
            for (int reg = 0; reg < 4; ++reg) {
                int rib = rt * 16 + g4 * 4 + reg;
                sP[rib][wave] = sv[rt][reg];
                qP[rib][wave] = qv[rt][reg];
            }
    }
    __syncthreads();

#pragma unroll
    for (int rt = 0; rt < 2; ++rt) {
#pragma unroll
        for (int reg = 0; reg < 4; ++reg) {
            int rib = rt * 16 + g4 * 4 + reg;
            float s = sP[rib][0] + sP[rib][1] + sP[rib][2] + sP[rib][3];
            float q = qP[rib][0] + qP[rib][1] + qP[rib][2] + qP[rib][3];
            float mu = s * (1.0f / (float)DOUT);
            float var = q * (1.0f / (float)DOUT) - mu * mu;
            float rs = rsqrtf(fmaxf(var, 0.f) + 1e-5f);
            int r = row0 + rib;
#pragma unroll
            for (int ct = 0; ct < CT; ++ct) {
                float y = (v[rt][reg][ct] - mu) * rs * gv[ct] + bbv[ct];
                if (EPI == 1) {
                    if (r < n) {
                        // residual = Xb row (LDS k = 128+col, swizzled)
                        ushort rh = *(const ushort*)((const char*)As + rib * 512 +
                                                     ((256 + 2 * colv[ct]) ^ ((rib & 7) << 4)));
                        y = gelu_f(y) + b2f(rh);
                        OutB[(size_t)r * DOUT + colv[ct]] = f2b(y);
                    }
                } else {
                    // stash LN'd y into swizzled LDS for the fused matvec
                    *(ushort*)((char*)Ys + rib * 128 +
                               ((2 * colv[ct]) ^ ((rib & 7) << 4))) = f2b(y);
                }
            }
        }
    }

    if (EPI == 3) {
        __syncthreads();
        // fused classifier matvec: Out = Ys @ Wct^T + bcls (4 MFMA, no shfl)
        const int col = wave * 16 + l16;
        bf16x8 b2r[2];
#pragma unroll
        for (int ks = 0; ks < 2; ++ks)
            b2r[ks] = *(const bf16x8*)(Wct + (size_t)col * 64 + ks * 32 + g4 * 8);
        f32x4 acc2[2];
#pragma unroll
        for (int rt = 0; rt < 2; ++rt) {
            acc2[rt][0] = 0.f;
            acc2[rt][1] = 0.f;
            acc2[rt][2] = 0.f;
            acc2[rt][3] = 0.f;
        }
#pragma unroll
        for (int ks = 0; ks < 2; ++ks)
#pragma unroll
            for (int rt = 0; rt < 2; ++rt) {
                const int row = rt * 16 + l16;
                bf16x8 a = *(const bf16x8*)((const char*)Ys + row * 128 +
                                            ((ks * 64 + g4 * 16) ^ ((row & 7) << 4)));
                acc2[rt] = __builtin_amdgcn_mfma_f32_16x16x32_bf16(a, b2r[ks], acc2[rt], 0, 0, 0);
            }
        const float bcv = (col < 40) ? bcls[col] : 0.f;
#pragma unroll
        for (int rt = 0; rt < 2; ++rt)
#pragma unroll
            for (int reg = 0; reg < 4; ++reg) {
                int r = row0 + rt * 16 + g4 * 4 + reg;
                if (r < n && col < 40) OutF[(size_t)r * 40 + col] = acc2[rt][reg] + bcv;
            }
    }
}

// ---------------------------------------------------------------------------

extern "C" void kernel_launch(void* const* d_in, const int* in_sizes, int n_in,
                              void* d_out, int out_size, void* d_ws, size_t ws_size,
                              hipStream_t stream) {
    const float* x   = (const float*)d_in[0];
    const int* ei    = (const int*)d_in[1];
    const float* Wl1 = (const float*)d_in[2];
    const float* bl1 = (const float*)d_in[3];
    const float* Wr1 = (const float*)d_in[4];
    const float* g1  = (const float*)d_in[5];
    const float* b1  = (const float*)d_in[6];
    const float* Wl2 = (const float*)d_in[7];
    const float* bl2 = (const float*)d_in[8];
    const float* Wr2 = (const float*)d_in[9];
    const float* g2  = (const float*)d_in[10];
    const float* b2  = (const float*)d_in[11];
    const float* Wl3 = (const float*)d_in[12];
    const float* bl3 = (const float*)d_in[13];
    const float* Wr3 = (const float*)d_in[14];
    const float* gc  = (const float*)d_in[15];
    const float* bc  = (const float*)d_in[16];
    const float* Wc  = (const float*)d_in[17];
    const float* bcls= (const float*)d_in[18];

    const int n = in_sizes[0] / 128;  // 50000
    const int e = in_sizes[1] / 2;    // 800000
    const int* src = ei;
    const int* dst = ei + e;

    char* w = (char*)d_ws;
    size_t o = 0;
    auto alloc = [&](size_t bytes) -> char* {
        char* p = w + o;
        o = (o + bytes + 511) & ~(size_t)511;
        return p;
    };
    int* cnts    = (int*)alloc((size_t)NBK * NWG * 4);
    int* bases   = (int*)alloc((size_t)NBK * NWG * 4);
    int* part    = (int*)alloc(256 * 4);
    uint* pairs  = (uint*)alloc((size_t)e * 4);
    int* csr     = (int*)alloc((size_t)e * 4);
    int* off     = (int*)alloc((size_t)n * 4);
    int* cnt     = (int*)alloc((size_t)n * 4);
    ushort* xB   = (ushort*)alloc((size_t)n * 128 * 2);
    ushort* aggB = (ushort*)alloc((size_t)n * 128 * 2);
    ushort* xaB  = (ushort*)alloc((size_t)n * 128 * 2);
    ushort* xbB  = (ushort*)alloc((size_t)n * 128 * 2);
    ushort* W1t  = (ushort*)alloc((size_t)128 * 256 * 2);
    ushort* W2t  = (ushort*)alloc((size_t)128 * 256 * 2);
    ushort* W3t  = (ushort*)alloc((size_t)64 * 256 * 2);
    ushort* Wct  = (ushort*)alloc((size_t)64 * 64 * 2);
    (void)ws_size;

    // merged prep: hist + cast + all weight packs in one dispatch
    k_prep<<<NWG + 2048 + 336, 256, 0, stream>>>(dst, e, cnts, x, xB, n * 128 / 4,
                                                 Wl1, Wr1, W1t, Wl2, Wr2, W2t,
                                                 Wl3, Wr3, W3t, Wc, Wct);

    // CSR build: scan -> scatter -> per-bucket sort (no global atomics)
    const int m = NBK * NWG;              // 50176
    const int sblk = (m + 1023) / 1024;   // 49
    k_scanP1<<<sblk, 256, 0, stream>>>(cnts, bases, part, m);
    k_scanP2<<<sblk, 256, 0, stream>>>(bases, part, m);
    k_scat<<<NWG, 256, 0, stream>>>(src, dst, e, bases, pairs);
    k_sortC<<<NBK, 256, 0, stream>>>(pairs, bases, e, csr, off, cnt, n);

    const int gg = (n + 31) / 32;  // shared grid: agg + gemm

    // block 1
    k_agg<<<gg, 256, 0, stream>>>(xB, off, cnt, csr, aggB, n);
    k_gemm<128, 1><<<gg, 256, 0, stream>>>(aggB, xB, W1t, bl1, g1, b1, xaB,
                                           nullptr, nullptr, nullptr, n);
    // block 2
    k_agg<<<gg, 256, 0, stream>>>(xaB, off, cnt, csr, aggB, n);
    k_gemm<128, 1><<<gg, 256, 0, stream>>>(aggB, xaB, W2t, bl2, g2, b2, xbB,
                                           nullptr, nullptr, nullptr, n);
    // conv_out + GELU + classifier LN + classifier matvec (all fused)
    k_agg<<<gg, 256, 0, stream>>>(xbB, off, cnt, csr, aggB, n);
    k_gemm<64, 3><<<gg, 256, 0, stream>>>(aggB, xbB, W3t, bl3, gc, bc, nullptr,
                                          Wct, bcls, (float*)d_out, n);
}